// Round 1
// baseline (508.283 us; speedup 1.0000x reference)
//
#include <hip/hip_runtime.h>
#include <hip/hip_bf16.h>

#define N_NODES 20000
#define E_EDGES 320000
#define NH 8
#define NC 32
#define HC 256
#define FIN 41
#define NG 64

// ---------------- CSR build ----------------

__global__ __launch_bounds__(256) void init_counts(int* cnt) {
    int n = blockIdx.x * 256 + threadIdx.x;
    if (n < N_NODES) cnt[n] = 1;  // self loop
}

__global__ __launch_bounds__(256) void hist(const int* __restrict__ ei, int* cnt) {
    int e = blockIdx.x * 256 + threadIdx.x;
    if (e < E_EDGES) atomicAdd(&cnt[ei[E_EDGES + e]], 1);
}

__global__ __launch_bounds__(512) void scanA(const int* __restrict__ cnt, int* partial) {
    __shared__ int red[512];
    int n = blockIdx.x * 512 + threadIdx.x;
    int v = (n < N_NODES) ? cnt[n] : 0;
    red[threadIdx.x] = v; __syncthreads();
    for (int off = 256; off > 0; off >>= 1) {
        if (threadIdx.x < off) red[threadIdx.x] += red[threadIdx.x + off];
        __syncthreads();
    }
    if (threadIdx.x == 0) partial[blockIdx.x] = red[0];
}

__global__ __launch_bounds__(64) void scanB(int* partial) {
    int t = threadIdx.x;
    int v = (t < 40) ? partial[t] : 0;
    int orig = v;
    for (int off = 1; off < 64; off <<= 1) {
        int y = __shfl_up(v, off);
        if (t >= off) v += y;
    }
    if (t < 40) partial[t] = v - orig;  // exclusive
}

__global__ __launch_bounds__(512) void scanC(const int* __restrict__ cnt, const int* __restrict__ partial,
                                             int* row_ptr, int* cursor, int* colidx) {
    __shared__ int buf[512];
    int t = threadIdx.x;
    int n = blockIdx.x * 512 + t;
    int v = (n < N_NODES) ? cnt[n] : 0;
    int x = v;
    buf[t] = x; __syncthreads();
    for (int off = 1; off < 512; off <<= 1) {
        int y = (t >= off) ? buf[t - off] : 0;
        __syncthreads();
        x += y; buf[t] = x; __syncthreads();
    }
    int excl = partial[blockIdx.x] + x - v;
    if (n < N_NODES) {
        row_ptr[n] = excl;
        cursor[n] = excl + 1;     // self loop occupies slot 0
        colidx[excl] = n;         // self loop
    }
    if (n == 0) row_ptr[N_NODES] = E_EDGES + N_NODES;
}

__global__ __launch_bounds__(256) void fill_csr(const int* __restrict__ ei, int* cursor, int* colidx) {
    int e = blockIdx.x * 256 + threadIdx.x;
    if (e >= E_EDGES) return;
    int d = ei[E_EDGES + e];
    int s = ei[e];
    int pos = atomicAdd(&cursor[d], 1);
    colidx[pos] = s;
}

// ---------------- GEMM: Hout[N,256] = X[N,K] @ W[K,256] ----------------

template <int K>
__global__ __launch_bounds__(256) void gemm_k(const float* __restrict__ X,
                                              const float* __restrict__ W,
                                              float* __restrict__ Hout) {
    __shared__ float xs[32][K + 1];
    int row0 = blockIdx.x * 32;
    int t = threadIdx.x;
    for (int idx = t; idx < 32 * K; idx += 256) {
        int r = idx / K, k = idx - r * K;
        int gr = row0 + r;
        xs[r][k] = (gr < N_NODES) ? X[(size_t)gr * K + k] : 0.f;
    }
    __syncthreads();
    float acc[32];
#pragma unroll
    for (int r = 0; r < 32; ++r) acc[r] = 0.f;
    for (int k = 0; k < K; ++k) {
        float wv = W[k * HC + t];
#pragma unroll
        for (int r = 0; r < 32; ++r) acc[r] += xs[r][k] * wv;
    }
#pragma unroll
    for (int r = 0; r < 32; ++r) {
        int gr = row0 + r;
        if (gr < N_NODES) Hout[(size_t)gr * HC + t] = acc[r];
    }
}

// ---------------- attention score dots: ssrc/sdst [N,8] ----------------

__global__ __launch_bounds__(256) void sdot(const float* __restrict__ h,
                                            const float* __restrict__ a_src,
                                            const float* __restrict__ a_dst,
                                            float* __restrict__ ssrc, float* __restrict__ sdst) {
    int wave = (blockIdx.x * blockDim.x + threadIdx.x) >> 6;
    int lane = threadIdx.x & 63;
    if (wave >= N_NODES) return;
    const float4 hv = *reinterpret_cast<const float4*>(h + (size_t)wave * HC + lane * 4);
    const float4 as = *reinterpret_cast<const float4*>(a_src + lane * 4);
    const float4 ad = *reinterpret_cast<const float4*>(a_dst + lane * 4);
    float ps = hv.x * as.x + hv.y * as.y + hv.z * as.z + hv.w * as.w;
    float pd = hv.x * ad.x + hv.y * ad.y + hv.z * ad.z + hv.w * ad.w;
    ps += __shfl_xor(ps, 1); pd += __shfl_xor(pd, 1);
    ps += __shfl_xor(ps, 2); pd += __shfl_xor(pd, 2);
    ps += __shfl_xor(ps, 4); pd += __shfl_xor(pd, 4);
    if ((lane & 7) == 0) {
        ssrc[wave * NH + (lane >> 3)] = ps;
        sdst[wave * NH + (lane >> 3)] = pd;
    }
}

// ---------------- fused GAT aggregation + bias + BN(eval) + ELU ----------------
// one wave per dst node; lane owns channels [lane*4, lane*4+4), head = lane>>3

__global__ __launch_bounds__(256) void gat_agg(const int* __restrict__ row_ptr,
                                               const int* __restrict__ colidx,
                                               const float* __restrict__ ssrc,
                                               const float* __restrict__ sdst,
                                               const float* __restrict__ h,
                                               const float* __restrict__ bias,
                                               const float* __restrict__ gamma,
                                               const float* __restrict__ beta,
                                               float* __restrict__ out) {
    int wave = (blockIdx.x * blockDim.x + threadIdx.x) >> 6;
    int lane = threadIdx.x & 63;
    if (wave >= N_NODES) return;
    int n = wave;
    int beg = row_ptr[n], end = row_ptr[n + 1];
    int deg = end - beg;

    // phase 1: per-head max of leaky_relu(ssrc[src]+sdst[n]); lane = (edge slot lane>>3, head lane&7)
    int hd1 = lane & 7;
    float sd1 = sdst[n * NH + hd1];
    float mx = -3.0e38f;
    for (int i = (lane >> 3); i < deg; i += 8) {
        int s = colidx[beg + i];
        float v = ssrc[s * NH + hd1] + sd1;
        v = (v >= 0.f) ? v : 0.2f * v;
        mx = fmaxf(mx, v);
    }
    mx = fmaxf(mx, __shfl_xor(mx, 8));
    mx = fmaxf(mx, __shfl_xor(mx, 16));
    mx = fmaxf(mx, __shfl_xor(mx, 32));
    // lanes 0..7 hold head 0..7 max (and replicated at lane&7)

    // phase 2: accumulate; lane's head is lane>>3
    int hd2 = lane >> 3;
    float m2 = __shfl(mx, hd2);
    float sd2 = sdst[n * NH + hd2];
    float acc0 = 0.f, acc1 = 0.f, acc2 = 0.f, acc3 = 0.f, denom = 0.f;
    for (int i = 0; i < deg; ++i) {
        int s = colidx[beg + i];
        float v = ssrc[s * NH + hd2] + sd2;
        v = (v >= 0.f) ? v : 0.2f * v;
        float wgt = __expf(v - m2);
        denom += wgt;
        const float4 hv = *reinterpret_cast<const float4*>(h + (size_t)s * HC + lane * 4);
        acc0 += wgt * hv.x; acc1 += wgt * hv.y; acc2 += wgt * hv.z; acc3 += wgt * hv.w;
    }
    float inv = 1.0f / denom;
    const float bninv = 0.99999500003749981f;  // 1/sqrt(1+1e-5)
    int c = lane * 4;
    float vals[4] = {acc0, acc1, acc2, acc3};
    float4 o;
    float* po = &o.x;
#pragma unroll
    for (int j = 0; j < 4; ++j) {
        float v = vals[j] * inv + bias[c + j];
        v = v * (gamma[c + j] * bninv) + beta[c + j];
        v = (v > 0.f) ? v : (__expf(v) - 1.0f);
        po[j] = v;
    }
    *reinterpret_cast<float4*>(out + (size_t)n * HC + c) = o;
}

// ---------------- pooling ----------------

__global__ __launch_bounds__(256) void graph_ranges(const int* __restrict__ batch, int* gstart, int* gend) {
    int n = blockIdx.x * 256 + threadIdx.x;
    if (n >= N_NODES) return;
    int b = batch[n];
    if (n == 0) gstart[b] = 0;
    else {
        int pb = batch[n - 1];
        if (pb != b) { gstart[b] = n; gend[pb] = n; }
    }
    if (n == N_NODES - 1) gend[b] = N_NODES;
}

__global__ __launch_bounds__(256) void pool(const float* __restrict__ h,
                                            const int* __restrict__ gstart,
                                            const int* __restrict__ gend,
                                            const float* __restrict__ gsz,
                                            float* __restrict__ p) {
    int g = blockIdx.x;
    int t = threadIdx.x;
    int s = gstart[g], e = gend[g];
    float sum = 0.f, mx = -3.0e38f;
    for (int n = s; n < e; ++n) {
        float v = h[(size_t)n * HC + t];
        sum += v;
        mx = fmaxf(mx, v);
    }
    float cnt = (float)(e - s);
    p[g * 514 + t] = sum / fmaxf(cnt, 1.f);
    p[g * 514 + 256 + t] = mx;
    if (t < 2) p[g * 514 + 512 + t] = gsz[g * 2 + t];
}

// ---------------- MLP head ----------------

__global__ __launch_bounds__(64) void mlp(const float* __restrict__ p,
                                          const float* __restrict__ fc1w, const float* __restrict__ fc1b,
                                          const float* __restrict__ gf1, const float* __restrict__ bf1,
                                          const float* __restrict__ fc2w, const float* __restrict__ fc2b,
                                          const float* __restrict__ gf2, const float* __restrict__ bf2,
                                          const float* __restrict__ fc3w, const float* __restrict__ fc3b,
                                          float* __restrict__ out) {
    __shared__ float pr[514];
    __shared__ float z1[64];
    __shared__ float z2[32];
    int g = blockIdx.x;
    int t = threadIdx.x;
    for (int i = t; i < 514; i += 64) pr[i] = p[g * 514 + i];
    __syncthreads();
    const float bninv = 0.99999500003749981f;
    float a = 0.f;
    for (int k = 0; k < 514; ++k) a += pr[k] * fc1w[k * 64 + t];
    a += fc1b[t];
    a = a * (gf1[t] * bninv) + bf1[t];
    z1[t] = fmaxf(a, 0.f);
    __syncthreads();
    if (t < 32) {
        float b = 0.f;
        for (int k = 0; k < 64; ++k) b += z1[k] * fc2w[k * 32 + t];
        b += fc2b[t];
        b = b * (gf2[t] * bninv) + bf2[t];
        z2[t] = fmaxf(b, 0.f);
    }
    __syncthreads();
    if (t < 2) {
        float c = 0.f;
        for (int k = 0; k < 32; ++k) c += z2[k] * fc3w[k * 2 + t];
        out[g * 2 + t] = c + fc3b[t];
    }
}

// ---------------- launch ----------------

extern "C" void kernel_launch(void* const* d_in, const int* in_sizes, int n_in,
                              void* d_out, int out_size, void* d_ws, size_t ws_size,
                              hipStream_t stream) {
    const float* x    = (const float*)d_in[0];
    const int*   ei   = (const int*)d_in[1];
    const int*   batch= (const int*)d_in[2];
    const float* gsz  = (const float*)d_in[3];
    const float* W1   = (const float*)d_in[4];
    const float* as1  = (const float*)d_in[5];
    const float* ad1  = (const float*)d_in[6];
    const float* b1   = (const float*)d_in[7];
    const float* g1   = (const float*)d_in[8];
    const float* be1  = (const float*)d_in[9];
    const float* W2   = (const float*)d_in[10];
    const float* as2  = (const float*)d_in[11];
    const float* ad2  = (const float*)d_in[12];
    const float* b2   = (const float*)d_in[13];
    const float* g2   = (const float*)d_in[14];
    const float* be2  = (const float*)d_in[15];
    const float* fc1w = (const float*)d_in[16];
    const float* fc1b = (const float*)d_in[17];
    const float* gf1  = (const float*)d_in[18];
    const float* bf1  = (const float*)d_in[19];
    const float* fc2w = (const float*)d_in[20];
    const float* fc2b = (const float*)d_in[21];
    const float* gf2  = (const float*)d_in[22];
    const float* bf2  = (const float*)d_in[23];
    const float* fc3w = (const float*)d_in[24];
    const float* fc3b = (const float*)d_in[25];
    float* out = (float*)d_out;

    char* w = (char*)d_ws;
    float* hbuf   = (float*)w; w += (size_t)N_NODES * HC * 4;
    float* actbuf = (float*)w; w += (size_t)N_NODES * HC * 4;
    float* ssrc   = (float*)w; w += (size_t)N_NODES * NH * 4;
    float* sdst   = (float*)w; w += (size_t)N_NODES * NH * 4;
    int* row_ptr  = (int*)w;   w += (size_t)(N_NODES + 1) * 4;
    int* cursor   = (int*)w;   w += (size_t)N_NODES * 4;
    int* cnt      = (int*)w;   w += (size_t)N_NODES * 4;
    int* colidx   = (int*)w;   w += (size_t)(E_EDGES + N_NODES) * 4;
    int* partial  = (int*)w;   w += 64 * 4;
    int* gstart   = (int*)w;   w += 64 * 4;
    int* gend     = (int*)w;   w += 64 * 4;
    float* pbuf   = (float*)w; w += (size_t)NG * 514 * 4;

    hipMemsetAsync(gstart, 0, 2 * 64 * 4, stream);

    init_counts<<<79, 256, 0, stream>>>(cnt);
    hist<<<1250, 256, 0, stream>>>(ei, cnt);
    scanA<<<40, 512, 0, stream>>>(cnt, partial);
    scanB<<<1, 64, 0, stream>>>(partial);
    scanC<<<40, 512, 0, stream>>>(cnt, partial, row_ptr, cursor, colidx);
    fill_csr<<<1250, 256, 0, stream>>>(ei, cursor, colidx);

    gemm_k<FIN><<<625, 256, 0, stream>>>(x, W1, hbuf);
    sdot<<<5000, 256, 0, stream>>>(hbuf, as1, ad1, ssrc, sdst);
    gat_agg<<<5000, 256, 0, stream>>>(row_ptr, colidx, ssrc, sdst, hbuf, b1, g1, be1, actbuf);

    gemm_k<HC><<<625, 256, 0, stream>>>(actbuf, W2, hbuf);
    sdot<<<5000, 256, 0, stream>>>(hbuf, as2, ad2, ssrc, sdst);
    gat_agg<<<5000, 256, 0, stream>>>(row_ptr, colidx, ssrc, sdst, hbuf, b2, g2, be2, actbuf);

    graph_ranges<<<79, 256, 0, stream>>>(batch, gstart, gend);
    pool<<<NG, 256, 0, stream>>>(actbuf, gstart, gend, gsz, pbuf);
    mlp<<<NG, 64, 0, stream>>>(pbuf, fc1w, fc1b, gf1, bf1, fc2w, fc2b, gf2, bf2, fc3w, fc3b, out);
}

// Round 2
// 420.710 us; speedup vs baseline: 1.2082x; 1.2082x over previous
//
#include <hip/hip_runtime.h>
#include <hip/hip_bf16.h>

#define N_NODES 20000
#define E_EDGES 320000
#define NH 8
#define NC 32
#define HC 256
#define FIN 41
#define NG 64

// ---------------- CSR build ----------------

__global__ __launch_bounds__(256) void init_counts(int* cnt) {
    int n = blockIdx.x * 256 + threadIdx.x;
    if (n < N_NODES) cnt[n] = 1;  // self loop
}

__global__ __launch_bounds__(256) void hist(const int* __restrict__ ei, int* cnt) {
    int e = blockIdx.x * 256 + threadIdx.x;
    if (e < E_EDGES) atomicAdd(&cnt[ei[E_EDGES + e]], 1);
}

__global__ __launch_bounds__(512) void scanA(const int* __restrict__ cnt, int* partial) {
    __shared__ int red[512];
    int n = blockIdx.x * 512 + threadIdx.x;
    int v = (n < N_NODES) ? cnt[n] : 0;
    red[threadIdx.x] = v; __syncthreads();
    for (int off = 256; off > 0; off >>= 1) {
        if (threadIdx.x < off) red[threadIdx.x] += red[threadIdx.x + off];
        __syncthreads();
    }
    if (threadIdx.x == 0) partial[blockIdx.x] = red[0];
}

__global__ __launch_bounds__(64) void scanB(int* partial) {
    int t = threadIdx.x;
    int v = (t < 40) ? partial[t] : 0;
    int orig = v;
    for (int off = 1; off < 64; off <<= 1) {
        int y = __shfl_up(v, off);
        if (t >= off) v += y;
    }
    if (t < 40) partial[t] = v - orig;  // exclusive
}

__global__ __launch_bounds__(512) void scanC(const int* __restrict__ cnt, const int* __restrict__ partial,
                                             int* row_ptr, int* cursor, int* colidx) {
    __shared__ int buf[512];
    int t = threadIdx.x;
    int n = blockIdx.x * 512 + t;
    int v = (n < N_NODES) ? cnt[n] : 0;
    int x = v;
    buf[t] = x; __syncthreads();
    for (int off = 1; off < 512; off <<= 1) {
        int y = (t >= off) ? buf[t - off] : 0;
        __syncthreads();
        x += y; buf[t] = x; __syncthreads();
    }
    int excl = partial[blockIdx.x] + x - v;
    if (n < N_NODES) {
        row_ptr[n] = excl;
        cursor[n] = excl + 1;     // self loop occupies slot 0
        colidx[excl] = n;         // self loop
    }
    if (n == 0) row_ptr[N_NODES] = E_EDGES + N_NODES;
}

__global__ __launch_bounds__(256) void fill_csr(const int* __restrict__ ei, int* cursor, int* colidx) {
    int e = blockIdx.x * 256 + threadIdx.x;
    if (e >= E_EDGES) return;
    int d = ei[E_EDGES + e];
    int s = ei[e];
    int pos = atomicAdd(&cursor[d], 1);
    colidx[pos] = s;
}

// ---------------- GEMM K=256: Hout[N,256] = X[N,256] @ W[256,256] ----------------
// 64-row x 256-col block tile. 4 waves; wave owns 16 rows; lane owns 4 cols.
// K chunked by 32 through LDS; W streamed (L1/L2-resident, reused by all blocks).

__global__ __launch_bounds__(256) void gemm256(const float* __restrict__ X,
                                               const float* __restrict__ W,
                                               float* __restrict__ Hout) {
    __shared__ float xs[64][36];
    int row0 = blockIdx.x * 64;
    int tid = threadIdx.x;
    int lane = tid & 63;
    int wave = tid >> 6;
    int c4 = lane * 4;
    int wrow = wave * 16;
    int lr = tid >> 3;   // 0..31 staging row
    int lf = tid & 7;    // 0..7 staging float4-slot

    float4 acc[16];
#pragma unroll
    for (int r = 0; r < 16; ++r) acc[r] = make_float4(0.f, 0.f, 0.f, 0.f);

    for (int k0 = 0; k0 < 256; k0 += 32) {
        __syncthreads();
#pragma unroll
        for (int half = 0; half < 2; ++half) {
            int r = lr + half * 32;
            int gr = row0 + r;
            float4 v = make_float4(0.f, 0.f, 0.f, 0.f);
            if (gr < N_NODES) v = *reinterpret_cast<const float4*>(X + (size_t)gr * 256 + k0 + lf * 4);
            *reinterpret_cast<float4*>(&xs[r][lf * 4]) = v;
        }
        __syncthreads();
        for (int k = 0; k < 32; k += 4) {
            const float* wp = W + (size_t)(k0 + k) * HC + c4;
            float4 w0 = *reinterpret_cast<const float4*>(wp);
            float4 w1 = *reinterpret_cast<const float4*>(wp + HC);
            float4 w2 = *reinterpret_cast<const float4*>(wp + 2 * HC);
            float4 w3 = *reinterpret_cast<const float4*>(wp + 3 * HC);
#pragma unroll
            for (int r = 0; r < 16; ++r) {
                float4 xv = *reinterpret_cast<const float4*>(&xs[wrow + r][k]);
                acc[r].x += xv.x * w0.x; acc[r].y += xv.x * w0.y; acc[r].z += xv.x * w0.z; acc[r].w += xv.x * w0.w;
                acc[r].x += xv.y * w1.x; acc[r].y += xv.y * w1.y; acc[r].z += xv.y * w1.z; acc[r].w += xv.y * w1.w;
                acc[r].x += xv.z * w2.x; acc[r].y += xv.z * w2.y; acc[r].z += xv.z * w2.z; acc[r].w += xv.z * w2.w;
                acc[r].x += xv.w * w3.x; acc[r].y += xv.w * w3.y; acc[r].z += xv.w * w3.z; acc[r].w += xv.w * w3.w;
            }
        }
    }
#pragma unroll
    for (int r = 0; r < 16; ++r) {
        int gr = row0 + wrow + r;
        if (gr < N_NODES) *reinterpret_cast<float4*>(Hout + (size_t)gr * HC + c4) = acc[r];
    }
}

// ---------------- GEMM K=41 ----------------

__global__ __launch_bounds__(256) void gemm41(const float* __restrict__ X,
                                              const float* __restrict__ W,
                                              float* __restrict__ Hout) {
    __shared__ float xs[64][44];
    int row0 = blockIdx.x * 64;
    int tid = threadIdx.x;
    int lane = tid & 63;
    int wave = tid >> 6;
    int c4 = lane * 4;
    int wrow = wave * 16;

    for (int idx = tid; idx < 64 * FIN; idx += 256) {
        int r = idx / FIN, k = idx - r * FIN;
        int gr = row0 + r;
        xs[r][k] = (gr < N_NODES) ? X[(size_t)gr * FIN + k] : 0.f;
    }
    __syncthreads();

    float4 acc[16];
#pragma unroll
    for (int r = 0; r < 16; ++r) acc[r] = make_float4(0.f, 0.f, 0.f, 0.f);

    for (int k = 0; k < FIN; ++k) {
        float4 w0 = *reinterpret_cast<const float4*>(W + (size_t)k * HC + c4);
#pragma unroll
        for (int r = 0; r < 16; ++r) {
            float xv = xs[wrow + r][k];
            acc[r].x += xv * w0.x; acc[r].y += xv * w0.y; acc[r].z += xv * w0.z; acc[r].w += xv * w0.w;
        }
    }
#pragma unroll
    for (int r = 0; r < 16; ++r) {
        int gr = row0 + wrow + r;
        if (gr < N_NODES) *reinterpret_cast<float4*>(Hout + (size_t)gr * HC + c4) = acc[r];
    }
}

// ---------------- attention score dots: ssrc/sdst [N,8] ----------------

__global__ __launch_bounds__(256) void sdot(const float* __restrict__ h,
                                            const float* __restrict__ a_src,
                                            const float* __restrict__ a_dst,
                                            float* __restrict__ ssrc, float* __restrict__ sdst) {
    int wave = (blockIdx.x * blockDim.x + threadIdx.x) >> 6;
    int lane = threadIdx.x & 63;
    if (wave >= N_NODES) return;
    const float4 hv = *reinterpret_cast<const float4*>(h + (size_t)wave * HC + lane * 4);
    const float4 as = *reinterpret_cast<const float4*>(a_src + lane * 4);
    const float4 ad = *reinterpret_cast<const float4*>(a_dst + lane * 4);
    float ps = hv.x * as.x + hv.y * as.y + hv.z * as.z + hv.w * as.w;
    float pd = hv.x * ad.x + hv.y * ad.y + hv.z * ad.z + hv.w * ad.w;
    ps += __shfl_xor(ps, 1); pd += __shfl_xor(pd, 1);
    ps += __shfl_xor(ps, 2); pd += __shfl_xor(pd, 2);
    ps += __shfl_xor(ps, 4); pd += __shfl_xor(pd, 4);
    if ((lane & 7) == 0) {
        ssrc[wave * NH + (lane >> 3)] = ps;
        sdst[wave * NH + (lane >> 3)] = pd;
    }
}

// ---------------- fused GAT aggregation + bias + BN(eval) + ELU ----------------

__global__ __launch_bounds__(256) void gat_agg(const int* __restrict__ row_ptr,
                                               const int* __restrict__ colidx,
                                               const float* __restrict__ ssrc,
                                               const float* __restrict__ sdst,
                                               const float* __restrict__ h,
                                               const float* __restrict__ bias,
                                               const float* __restrict__ gamma,
                                               const float* __restrict__ beta,
                                               float* __restrict__ out) {
    int wave = (blockIdx.x * blockDim.x + threadIdx.x) >> 6;
    int lane = threadIdx.x & 63;
    if (wave >= N_NODES) return;
    int n = wave;
    int beg = row_ptr[n], end = row_ptr[n + 1];
    int deg = end - beg;

    int hd1 = lane & 7;
    float sd1 = sdst[n * NH + hd1];
    float mx = -3.0e38f;
    for (int i = (lane >> 3); i < deg; i += 8) {
        int s = colidx[beg + i];
        float v = ssrc[s * NH + hd1] + sd1;
        v = (v >= 0.f) ? v : 0.2f * v;
        mx = fmaxf(mx, v);
    }
    mx = fmaxf(mx, __shfl_xor(mx, 8));
    mx = fmaxf(mx, __shfl_xor(mx, 16));
    mx = fmaxf(mx, __shfl_xor(mx, 32));

    int hd2 = lane >> 3;
    float m2 = __shfl(mx, hd2);
    float sd2 = sdst[n * NH + hd2];
    float acc0 = 0.f, acc1 = 0.f, acc2 = 0.f, acc3 = 0.f, denom = 0.f;
    for (int i = 0; i < deg; ++i) {
        int s = colidx[beg + i];
        float v = ssrc[s * NH + hd2] + sd2;
        v = (v >= 0.f) ? v : 0.2f * v;
        float wgt = __expf(v - m2);
        denom += wgt;
        const float4 hv = *reinterpret_cast<const float4*>(h + (size_t)s * HC + lane * 4);
        acc0 += wgt * hv.x; acc1 += wgt * hv.y; acc2 += wgt * hv.z; acc3 += wgt * hv.w;
    }
    float inv = 1.0f / denom;
    const float bninv = 0.99999500003749981f;  // 1/sqrt(1+1e-5)
    int c = lane * 4;
    float vals[4] = {acc0, acc1, acc2, acc3};
    float4 o;
    float* po = &o.x;
#pragma unroll
    for (int j = 0; j < 4; ++j) {
        float v = vals[j] * inv + bias[c + j];
        v = v * (gamma[c + j] * bninv) + beta[c + j];
        v = (v > 0.f) ? v : (__expf(v) - 1.0f);
        po[j] = v;
    }
    *reinterpret_cast<float4*>(out + (size_t)n * HC + c) = o;
}

// ---------------- pooling ----------------

__global__ __launch_bounds__(256) void graph_ranges(const int* __restrict__ batch, int* gstart, int* gend) {
    int n = blockIdx.x * 256 + threadIdx.x;
    if (n >= N_NODES) return;
    int b = batch[n];
    if (n == 0) gstart[b] = 0;
    else {
        int pb = batch[n - 1];
        if (pb != b) { gstart[b] = n; gend[pb] = n; }
    }
    if (n == N_NODES - 1) gend[b] = N_NODES;
}

__global__ __launch_bounds__(256) void pool(const float* __restrict__ h,
                                            const int* __restrict__ gstart,
                                            const int* __restrict__ gend,
                                            const float* __restrict__ gsz,
                                            float* __restrict__ p) {
    int g = blockIdx.x;
    int t = threadIdx.x;
    int s = gstart[g], e = gend[g];
    float sum = 0.f, mx = -3.0e38f;
    for (int n = s; n < e; ++n) {
        float v = h[(size_t)n * HC + t];
        sum += v;
        mx = fmaxf(mx, v);
    }
    float cnt = (float)(e - s);
    p[g * 514 + t] = sum / fmaxf(cnt, 1.f);
    p[g * 514 + 256 + t] = mx;
    if (t < 2) p[g * 514 + 512 + t] = gsz[g * 2 + t];
}

// ---------------- MLP head ----------------

__global__ __launch_bounds__(64) void mlp(const float* __restrict__ p,
                                          const float* __restrict__ fc1w, const float* __restrict__ fc1b,
                                          const float* __restrict__ gf1, const float* __restrict__ bf1,
                                          const float* __restrict__ fc2w, const float* __restrict__ fc2b,
                                          const float* __restrict__ gf2, const float* __restrict__ bf2,
                                          const float* __restrict__ fc3w, const float* __restrict__ fc3b,
                                          float* __restrict__ out) {
    __shared__ float pr[514];
    __shared__ float z1[64];
    __shared__ float z2[32];
    int g = blockIdx.x;
    int t = threadIdx.x;
    for (int i = t; i < 514; i += 64) pr[i] = p[g * 514 + i];
    __syncthreads();
    const float bninv = 0.99999500003749981f;
    float a = 0.f;
    for (int k = 0; k < 514; ++k) a += pr[k] * fc1w[k * 64 + t];
    a += fc1b[t];
    a = a * (gf1[t] * bninv) + bf1[t];
    z1[t] = fmaxf(a, 0.f);
    __syncthreads();
    if (t < 32) {
        float b = 0.f;
        for (int k = 0; k < 64; ++k) b += z1[k] * fc2w[k * 32 + t];
        b += fc2b[t];
        b = b * (gf2[t] * bninv) + bf2[t];
        z2[t] = fmaxf(b, 0.f);
    }
    __syncthreads();
    if (t < 2) {
        float c = 0.f;
        for (int k = 0; k < 32; ++k) c += z2[k] * fc3w[k * 2 + t];
        out[g * 2 + t] = c + fc3b[t];
    }
}

// ---------------- launch ----------------

extern "C" void kernel_launch(void* const* d_in, const int* in_sizes, int n_in,
                              void* d_out, int out_size, void* d_ws, size_t ws_size,
                              hipStream_t stream) {
    const float* x    = (const float*)d_in[0];
    const int*   ei   = (const int*)d_in[1];
    const int*   batch= (const int*)d_in[2];
    const float* gsz  = (const float*)d_in[3];
    const float* W1   = (const float*)d_in[4];
    const float* as1  = (const float*)d_in[5];
    const float* ad1  = (const float*)d_in[6];
    const float* b1   = (const float*)d_in[7];
    const float* g1   = (const float*)d_in[8];
    const float* be1  = (const float*)d_in[9];
    const float* W2   = (const float*)d_in[10];
    const float* as2  = (const float*)d_in[11];
    const float* ad2  = (const float*)d_in[12];
    const float* b2   = (const float*)d_in[13];
    const float* g2   = (const float*)d_in[14];
    const float* be2  = (const float*)d_in[15];
    const float* fc1w = (const float*)d_in[16];
    const float* fc1b = (const float*)d_in[17];
    const float* gf1  = (const float*)d_in[18];
    const float* bf1  = (const float*)d_in[19];
    const float* fc2w = (const float*)d_in[20];
    const float* fc2b = (const float*)d_in[21];
    const float* gf2  = (const float*)d_in[22];
    const float* bf2  = (const float*)d_in[23];
    const float* fc3w = (const float*)d_in[24];
    const float* fc3b = (const float*)d_in[25];
    float* out = (float*)d_out;

    char* w = (char*)d_ws;
    float* hbuf   = (float*)w; w += (size_t)N_NODES * HC * 4;
    float* actbuf = (float*)w; w += (size_t)N_NODES * HC * 4;
    float* ssrc   = (float*)w; w += (size_t)N_NODES * NH * 4;
    float* sdst   = (float*)w; w += (size_t)N_NODES * NH * 4;
    int* row_ptr  = (int*)w;   w += (size_t)(N_NODES + 1) * 4;
    int* cursor   = (int*)w;   w += (size_t)N_NODES * 4;
    int* cnt      = (int*)w;   w += (size_t)N_NODES * 4;
    int* colidx   = (int*)w;   w += (size_t)(E_EDGES + N_NODES) * 4;
    int* partial  = (int*)w;   w += 64 * 4;
    int* gstart   = (int*)w;   w += 64 * 4;
    int* gend     = (int*)w;   w += 64 * 4;
    float* pbuf   = (float*)w; w += (size_t)NG * 514 * 4;

    hipMemsetAsync(gstart, 0, 2 * 64 * 4, stream);

    init_counts<<<79, 256, 0, stream>>>(cnt);
    hist<<<1250, 256, 0, stream>>>(ei, cnt);
    scanA<<<40, 512, 0, stream>>>(cnt, partial);
    scanB<<<1, 64, 0, stream>>>(partial);
    scanC<<<40, 512, 0, stream>>>(cnt, partial, row_ptr, cursor, colidx);
    fill_csr<<<1250, 256, 0, stream>>>(ei, cursor, colidx);

    gemm41<<<313, 256, 0, stream>>>(x, W1, hbuf);
    sdot<<<5000, 256, 0, stream>>>(hbuf, as1, ad1, ssrc, sdst);
    gat_agg<<<5000, 256, 0, stream>>>(row_ptr, colidx, ssrc, sdst, hbuf, b1, g1, be1, actbuf);

    gemm256<<<313, 256, 0, stream>>>(actbuf, W2, hbuf);
    sdot<<<5000, 256, 0, stream>>>(hbuf, as2, ad2, ssrc, sdst);
    gat_agg<<<5000, 256, 0, stream>>>(row_ptr, colidx, ssrc, sdst, hbuf, b2, g2, be2, actbuf);

    graph_ranges<<<79, 256, 0, stream>>>(batch, gstart, gend);
    pool<<<NG, 256, 0, stream>>>(actbuf, gstart, gend, gsz, pbuf);
    mlp<<<NG, 64, 0, stream>>>(pbuf, fc1w, fc1b, gf1, bf1, fc2w, fc2b, gf2, bf2, fc3w, fc3b, out);
}

// Round 3
// 308.626 us; speedup vs baseline: 1.6469x; 1.3632x over previous
//
#include <hip/hip_runtime.h>
#include <hip/hip_bf16.h>

#define N_NODES 20000
#define E_EDGES 320000
#define NH 8
#define NC 32
#define HC 256
#define FIN 41
#define NG 64
#define PCHUNK 16

// ---------------- CSR build ----------------

__global__ __launch_bounds__(256) void init_counts(int* cnt) {
    int n = blockIdx.x * 256 + threadIdx.x;
    if (n < N_NODES) cnt[n] = 1;  // self loop
}

__global__ __launch_bounds__(256) void hist(const int* __restrict__ ei, int* cnt) {
    int e = blockIdx.x * 256 + threadIdx.x;
    if (e < E_EDGES) atomicAdd(&cnt[ei[E_EDGES + e]], 1);
}

__global__ __launch_bounds__(512) void scanA(const int* __restrict__ cnt, int* partial) {
    __shared__ int red[512];
    int n = blockIdx.x * 512 + threadIdx.x;
    int v = (n < N_NODES) ? cnt[n] : 0;
    red[threadIdx.x] = v; __syncthreads();
    for (int off = 256; off > 0; off >>= 1) {
        if (threadIdx.x < off) red[threadIdx.x] += red[threadIdx.x + off];
        __syncthreads();
    }
    if (threadIdx.x == 0) partial[blockIdx.x] = red[0];
}

__global__ __launch_bounds__(64) void scanB(int* partial) {
    int t = threadIdx.x;
    int v = (t < 40) ? partial[t] : 0;
    int orig = v;
    for (int off = 1; off < 64; off <<= 1) {
        int y = __shfl_up(v, off);
        if (t >= off) v += y;
    }
    if (t < 40) partial[t] = v - orig;  // exclusive
}

__global__ __launch_bounds__(512) void scanC(const int* __restrict__ cnt, const int* __restrict__ partial,
                                             int* row_ptr, int* cursor, int* colidx) {
    __shared__ int buf[512];
    int t = threadIdx.x;
    int n = blockIdx.x * 512 + t;
    int v = (n < N_NODES) ? cnt[n] : 0;
    int x = v;
    buf[t] = x; __syncthreads();
    for (int off = 1; off < 512; off <<= 1) {
        int y = (t >= off) ? buf[t - off] : 0;
        __syncthreads();
        x += y; buf[t] = x; __syncthreads();
    }
    int excl = partial[blockIdx.x] + x - v;
    if (n < N_NODES) {
        row_ptr[n] = excl;
        cursor[n] = excl + 1;     // self loop occupies slot 0
        colidx[excl] = n;         // self loop
    }
    if (n == 0) row_ptr[N_NODES] = E_EDGES + N_NODES;
}

__global__ __launch_bounds__(256) void fill_csr(const int* __restrict__ ei, int* cursor, int* colidx) {
    int e = blockIdx.x * 256 + threadIdx.x;
    if (e >= E_EDGES) return;
    int d = ei[E_EDGES + e];
    int s = ei[e];
    int pos = atomicAdd(&cursor[d], 1);
    colidx[pos] = s;
}

// ---------------- GEMM K=256 ----------------

__global__ __launch_bounds__(256) void gemm256(const float* __restrict__ X,
                                               const float* __restrict__ W,
                                               float* __restrict__ Hout) {
    __shared__ float xs[64][36];
    int row0 = blockIdx.x * 64;
    int tid = threadIdx.x;
    int lane = tid & 63;
    int wave = tid >> 6;
    int c4 = lane * 4;
    int wrow = wave * 16;
    int lr = tid >> 3;   // 0..31 staging row
    int lf = tid & 7;    // 0..7 staging float4-slot

    float4 acc[16];
#pragma unroll
    for (int r = 0; r < 16; ++r) acc[r] = make_float4(0.f, 0.f, 0.f, 0.f);

    for (int k0 = 0; k0 < 256; k0 += 32) {
        __syncthreads();
#pragma unroll
        for (int half = 0; half < 2; ++half) {
            int r = lr + half * 32;
            int gr = row0 + r;
            float4 v = make_float4(0.f, 0.f, 0.f, 0.f);
            if (gr < N_NODES) v = *reinterpret_cast<const float4*>(X + (size_t)gr * 256 + k0 + lf * 4);
            *reinterpret_cast<float4*>(&xs[r][lf * 4]) = v;
        }
        __syncthreads();
        for (int k = 0; k < 32; k += 4) {
            const float* wp = W + (size_t)(k0 + k) * HC + c4;
            float4 w0 = *reinterpret_cast<const float4*>(wp);
            float4 w1 = *reinterpret_cast<const float4*>(wp + HC);
            float4 w2 = *reinterpret_cast<const float4*>(wp + 2 * HC);
            float4 w3 = *reinterpret_cast<const float4*>(wp + 3 * HC);
#pragma unroll
            for (int r = 0; r < 16; ++r) {
                float4 xv = *reinterpret_cast<const float4*>(&xs[wrow + r][k]);
                acc[r].x += xv.x * w0.x; acc[r].y += xv.x * w0.y; acc[r].z += xv.x * w0.z; acc[r].w += xv.x * w0.w;
                acc[r].x += xv.y * w1.x; acc[r].y += xv.y * w1.y; acc[r].z += xv.y * w1.z; acc[r].w += xv.y * w1.w;
                acc[r].x += xv.z * w2.x; acc[r].y += xv.z * w2.y; acc[r].z += xv.z * w2.z; acc[r].w += xv.z * w2.w;
                acc[r].x += xv.w * w3.x; acc[r].y += xv.w * w3.y; acc[r].z += xv.w * w3.z; acc[r].w += xv.w * w3.w;
            }
        }
    }
#pragma unroll
    for (int r = 0; r < 16; ++r) {
        int gr = row0 + wrow + r;
        if (gr < N_NODES) *reinterpret_cast<float4*>(Hout + (size_t)gr * HC + c4) = acc[r];
    }
}

// ---------------- GEMM K=41 ----------------

__global__ __launch_bounds__(256) void gemm41(const float* __restrict__ X,
                                              const float* __restrict__ W,
                                              float* __restrict__ Hout) {
    __shared__ float xs[64][44];
    int row0 = blockIdx.x * 64;
    int tid = threadIdx.x;
    int lane = tid & 63;
    int wave = tid >> 6;
    int c4 = lane * 4;
    int wrow = wave * 16;

    for (int idx = tid; idx < 64 * FIN; idx += 256) {
        int r = idx / FIN, k = idx - r * FIN;
        int gr = row0 + r;
        xs[r][k] = (gr < N_NODES) ? X[(size_t)gr * FIN + k] : 0.f;
    }
    __syncthreads();

    float4 acc[16];
#pragma unroll
    for (int r = 0; r < 16; ++r) acc[r] = make_float4(0.f, 0.f, 0.f, 0.f);

    for (int k = 0; k < FIN; ++k) {
        float4 w0 = *reinterpret_cast<const float4*>(W + (size_t)k * HC + c4);
#pragma unroll
        for (int r = 0; r < 16; ++r) {
            float xv = xs[wrow + r][k];
            acc[r].x += xv * w0.x; acc[r].y += xv * w0.y; acc[r].z += xv * w0.z; acc[r].w += xv * w0.w;
        }
    }
#pragma unroll
    for (int r = 0; r < 16; ++r) {
        int gr = row0 + wrow + r;
        if (gr < N_NODES) *reinterpret_cast<float4*>(Hout + (size_t)gr * HC + c4) = acc[r];
    }
}

// ---------------- attention score dots ----------------

__global__ __launch_bounds__(256) void sdot(const float* __restrict__ h,
                                            const float* __restrict__ a_src,
                                            const float* __restrict__ a_dst,
                                            float* __restrict__ ssrc, float* __restrict__ sdst) {
    int wave = (blockIdx.x * blockDim.x + threadIdx.x) >> 6;
    int lane = threadIdx.x & 63;
    if (wave >= N_NODES) return;
    const float4 hv = *reinterpret_cast<const float4*>(h + (size_t)wave * HC + lane * 4);
    const float4 as = *reinterpret_cast<const float4*>(a_src + lane * 4);
    const float4 ad = *reinterpret_cast<const float4*>(a_dst + lane * 4);
    float ps = hv.x * as.x + hv.y * as.y + hv.z * as.z + hv.w * as.w;
    float pd = hv.x * ad.x + hv.y * ad.y + hv.z * ad.z + hv.w * ad.w;
    ps += __shfl_xor(ps, 1); pd += __shfl_xor(pd, 1);
    ps += __shfl_xor(ps, 2); pd += __shfl_xor(pd, 2);
    ps += __shfl_xor(ps, 4); pd += __shfl_xor(pd, 4);
    if ((lane & 7) == 0) {
        ssrc[wave * NH + (lane >> 3)] = ps;
        sdst[wave * NH + (lane >> 3)] = pd;
    }
}

// ---------------- fused GAT aggregation + bias + BN(eval) + ELU ----------------

__global__ __launch_bounds__(256) void gat_agg(const int* __restrict__ row_ptr,
                                               const int* __restrict__ colidx,
                                               const float* __restrict__ ssrc,
                                               const float* __restrict__ sdst,
                                               const float* __restrict__ h,
                                               const float* __restrict__ bias,
                                               const float* __restrict__ gamma,
                                               const float* __restrict__ beta,
                                               float* __restrict__ out) {
    int wave = (blockIdx.x * blockDim.x + threadIdx.x) >> 6;
    int lane = threadIdx.x & 63;
    if (wave >= N_NODES) return;
    int n = wave;
    int beg = row_ptr[n], end = row_ptr[n + 1];
    int deg = end - beg;

    int hd1 = lane & 7;
    float sd1 = sdst[n * NH + hd1];
    float mx = -3.0e38f;
    for (int i = (lane >> 3); i < deg; i += 8) {
        int s = colidx[beg + i];
        float v = ssrc[s * NH + hd1] + sd1;
        v = (v >= 0.f) ? v : 0.2f * v;
        mx = fmaxf(mx, v);
    }
    mx = fmaxf(mx, __shfl_xor(mx, 8));
    mx = fmaxf(mx, __shfl_xor(mx, 16));
    mx = fmaxf(mx, __shfl_xor(mx, 32));

    int hd2 = lane >> 3;
    float m2 = __shfl(mx, hd2);
    float sd2 = sdst[n * NH + hd2];
    float acc0 = 0.f, acc1 = 0.f, acc2 = 0.f, acc3 = 0.f, denom = 0.f;
    for (int i = 0; i < deg; ++i) {
        int s = colidx[beg + i];
        float v = ssrc[s * NH + hd2] + sd2;
        v = (v >= 0.f) ? v : 0.2f * v;
        float wgt = __expf(v - m2);
        denom += wgt;
        const float4 hv = *reinterpret_cast<const float4*>(h + (size_t)s * HC + lane * 4);
        acc0 += wgt * hv.x; acc1 += wgt * hv.y; acc2 += wgt * hv.z; acc3 += wgt * hv.w;
    }
    float inv = 1.0f / denom;
    const float bninv = 0.99999500003749981f;  // 1/sqrt(1+1e-5)
    int c = lane * 4;
    float vals[4] = {acc0, acc1, acc2, acc3};
    float4 o;
    float* po = &o.x;
#pragma unroll
    for (int j = 0; j < 4; ++j) {
        float v = vals[j] * inv + bias[c + j];
        v = v * (gamma[c + j] * bninv) + beta[c + j];
        v = (v > 0.f) ? v : (__expf(v) - 1.0f);
        po[j] = v;
    }
    *reinterpret_cast<float4*>(out + (size_t)n * HC + c) = o;
}

// ---------------- pooling ----------------

__global__ __launch_bounds__(256) void graph_ranges(const int* __restrict__ batch, int* gstart, int* gend) {
    int n = blockIdx.x * 256 + threadIdx.x;
    if (n >= N_NODES) return;
    int b = batch[n];
    if (n == 0) gstart[b] = 0;
    else {
        int pb = batch[n - 1];
        if (pb != b) { gstart[b] = n; gend[pb] = n; }
    }
    if (n == N_NODES - 1) gend[b] = N_NODES;
}

// partial pooling: block = (graph g, chunk c); deterministic fixed-slot partials
__global__ __launch_bounds__(256) void pool_partial(const float* __restrict__ h,
                                                    const int* __restrict__ gstart,
                                                    const int* __restrict__ gend,
                                                    float* __restrict__ psum,
                                                    float* __restrict__ pmax) {
    int g = blockIdx.x >> 4;
    int c = blockIdx.x & (PCHUNK - 1);
    int t = threadIdx.x;
    int s = gstart[g], e = gend[g];
    int len = e - s;
    int n0 = s + (int)(((long long)len * c) / PCHUNK);
    int n1 = s + (int)(((long long)len * (c + 1)) / PCHUNK);
    float sum = 0.f, mx = -3.0e38f;
    for (int n = n0; n < n1; ++n) {
        float v = h[(size_t)n * HC + t];
        sum += v;
        mx = fmaxf(mx, v);
    }
    psum[(size_t)(g * PCHUNK + c) * HC + t] = sum;
    pmax[(size_t)(g * PCHUNK + c) * HC + t] = mx;
}

// ---------------- MLP head (fused pool-finalize + 3 FC layers) ----------------

__global__ __launch_bounds__(256) void mlp(const float* __restrict__ psum,
                                           const float* __restrict__ pmax,
                                           const int* __restrict__ gstart,
                                           const int* __restrict__ gend,
                                           const float* __restrict__ gsz,
                                           const float* __restrict__ fc1w, const float* __restrict__ fc1b,
                                           const float* __restrict__ gf1, const float* __restrict__ bf1,
                                           const float* __restrict__ fc2w, const float* __restrict__ fc2b,
                                           const float* __restrict__ gf2, const float* __restrict__ bf2,
                                           const float* __restrict__ fc3w, const float* __restrict__ fc3b,
                                           float* __restrict__ out) {
    __shared__ float pr[514];
    __shared__ float zz1[4][64];
    __shared__ float z1[64];
    __shared__ float zz2[8][32];
    __shared__ float z2[32];
    int g = blockIdx.x;
    int t = threadIdx.x;
    const float bninv = 0.99999500003749981f;

    // phase 0: reduce pool partials
    {
        float s = 0.f, m = -3.0e38f;
#pragma unroll
        for (int c = 0; c < PCHUNK; ++c) {
            s += psum[(size_t)(g * PCHUNK + c) * HC + t];
            m = fmaxf(m, pmax[(size_t)(g * PCHUNK + c) * HC + t]);
        }
        float cnt = (float)(gend[g] - gstart[g]);
        pr[t] = s / fmaxf(cnt, 1.f);
        pr[256 + t] = m;
        if (t < 2) pr[512 + t] = gsz[g * 2 + t];
    }
    __syncthreads();

    // phase 1: fc1 (514 x 64), 4-way k-split
    {
        int u = t & 63, sp = t >> 6;
        int k0 = (514 * sp) / 4, k1 = (514 * (sp + 1)) / 4;
        float a = 0.f;
        for (int k = k0; k < k1; ++k) a += pr[k] * fc1w[k * 64 + u];
        zz1[sp][u] = a;
    }
    __syncthreads();
    if (t < 64) {
        float a = zz1[0][t] + zz1[1][t] + zz1[2][t] + zz1[3][t] + fc1b[t];
        a = a * (gf1[t] * bninv) + bf1[t];
        z1[t] = fmaxf(a, 0.f);
    }
    __syncthreads();

    // phase 2: fc2 (64 x 32), 8-way k-split
    {
        int u = t & 31, sp = t >> 5;
        float b = 0.f;
#pragma unroll
        for (int k = sp * 8; k < sp * 8 + 8; ++k) b += z1[k] * fc2w[k * 32 + u];
        zz2[sp][u] = b;
    }
    __syncthreads();
    if (t < 32) {
        float b = 0.f;
#pragma unroll
        for (int sp = 0; sp < 8; ++sp) b += zz2[sp][t];
        b += fc2b[t];
        b = b * (gf2[t] * bninv) + bf2[t];
        z2[t] = fmaxf(b, 0.f);
    }
    __syncthreads();

    // phase 3: fc3 (32 x 2)
    if (t < 2) {
        float c = 0.f;
#pragma unroll
        for (int k = 0; k < 32; ++k) c += z2[k] * fc3w[k * 2 + t];
        out[g * 2 + t] = c + fc3b[t];
    }
}

// ---------------- launch ----------------

extern "C" void kernel_launch(void* const* d_in, const int* in_sizes, int n_in,
                              void* d_out, int out_size, void* d_ws, size_t ws_size,
                              hipStream_t stream) {
    const float* x    = (const float*)d_in[0];
    const int*   ei   = (const int*)d_in[1];
    const int*   batch= (const int*)d_in[2];
    const float* gsz  = (const float*)d_in[3];
    const float* W1   = (const float*)d_in[4];
    const float* as1  = (const float*)d_in[5];
    const float* ad1  = (const float*)d_in[6];
    const float* b1   = (const float*)d_in[7];
    const float* g1   = (const float*)d_in[8];
    const float* be1  = (const float*)d_in[9];
    const float* W2   = (const float*)d_in[10];
    const float* as2  = (const float*)d_in[11];
    const float* ad2  = (const float*)d_in[12];
    const float* b2   = (const float*)d_in[13];
    const float* g2   = (const float*)d_in[14];
    const float* be2  = (const float*)d_in[15];
    const float* fc1w = (const float*)d_in[16];
    const float* fc1b = (const float*)d_in[17];
    const float* gf1  = (const float*)d_in[18];
    const float* bf1  = (const float*)d_in[19];
    const float* fc2w = (const float*)d_in[20];
    const float* fc2b = (const float*)d_in[21];
    const float* gf2  = (const float*)d_in[22];
    const float* bf2  = (const float*)d_in[23];
    const float* fc3w = (const float*)d_in[24];
    const float* fc3b = (const float*)d_in[25];
    float* out = (float*)d_out;

    char* w = (char*)d_ws;
    float* hbuf   = (float*)w; w += (size_t)N_NODES * HC * 4;
    float* actbuf = (float*)w; w += (size_t)N_NODES * HC * 4;
    float* ssrc   = (float*)w; w += (size_t)N_NODES * NH * 4;
    float* sdst   = (float*)w; w += (size_t)N_NODES * NH * 4;
    int* row_ptr  = (int*)w;   w += (size_t)(N_NODES + 1) * 4;
    int* cursor   = (int*)w;   w += (size_t)N_NODES * 4;
    int* cnt      = (int*)w;   w += (size_t)N_NODES * 4;
    int* colidx   = (int*)w;   w += (size_t)(E_EDGES + N_NODES) * 4;
    int* partial  = (int*)w;   w += 64 * 4;
    int* gstart   = (int*)w;   w += 64 * 4;
    int* gend     = (int*)w;   w += 64 * 4;

    // pool partials alias hbuf (dead after second gat_agg)
    float* psum = hbuf;
    float* pmax = hbuf + (size_t)NG * PCHUNK * HC;

    hipMemsetAsync(gstart, 0, 2 * 64 * 4, stream);

    init_counts<<<79, 256, 0, stream>>>(cnt);
    hist<<<1250, 256, 0, stream>>>(ei, cnt);
    scanA<<<40, 512, 0, stream>>>(cnt, partial);
    scanB<<<1, 64, 0, stream>>>(partial);
    scanC<<<40, 512, 0, stream>>>(cnt, partial, row_ptr, cursor, colidx);
    fill_csr<<<1250, 256, 0, stream>>>(ei, cursor, colidx);

    gemm41<<<313, 256, 0, stream>>>(x, W1, hbuf);
    sdot<<<5000, 256, 0, stream>>>(hbuf, as1, ad1, ssrc, sdst);
    gat_agg<<<5000, 256, 0, stream>>>(row_ptr, colidx, ssrc, sdst, hbuf, b1, g1, be1, actbuf);

    gemm256<<<313, 256, 0, stream>>>(actbuf, W2, hbuf);
    sdot<<<5000, 256, 0, stream>>>(hbuf, as2, ad2, ssrc, sdst);
    gat_agg<<<5000, 256, 0, stream>>>(row_ptr, colidx, ssrc, sdst, hbuf, b2, g2, be2, actbuf);

    graph_ranges<<<79, 256, 0, stream>>>(batch, gstart, gend);
    pool_partial<<<NG * PCHUNK, 256, 0, stream>>>(actbuf, gstart, gend, psum, pmax);
    mlp<<<NG, 256, 0, stream>>>(psum, pmax, gstart, gend, gsz,
                                fc1w, fc1b, gf1, bf1, fc2w, fc2b, gf2, bf2, fc3w, fc3b, out);
}

// Round 4
// 269.381 us; speedup vs baseline: 1.8869x; 1.1457x over previous
//
#include <hip/hip_runtime.h>
#include <hip/hip_bf16.h>

#define N_NODES 20000
#define E_EDGES 320000
#define NH 8
#define NC 32
#define HC 256
#define FIN 41
#define NG 64
#define PCHUNK 16

// ---------------- CSR build ----------------

__global__ __launch_bounds__(256) void init_counts(int* cnt) {
    int n = blockIdx.x * 256 + threadIdx.x;
    if (n < N_NODES) cnt[n] = 1;  // self loop
}

__global__ __launch_bounds__(256) void hist(const int* __restrict__ ei, int* cnt) {
    int e = blockIdx.x * 256 + threadIdx.x;
    if (e < E_EDGES) atomicAdd(&cnt[ei[E_EDGES + e]], 1);
}

__global__ __launch_bounds__(512) void scanA(const int* __restrict__ cnt, int* partial) {
    __shared__ int red[512];
    int n = blockIdx.x * 512 + threadIdx.x;
    int v = (n < N_NODES) ? cnt[n] : 0;
    red[threadIdx.x] = v; __syncthreads();
    for (int off = 256; off > 0; off >>= 1) {
        if (threadIdx.x < off) red[threadIdx.x] += red[threadIdx.x + off];
        __syncthreads();
    }
    if (threadIdx.x == 0) partial[blockIdx.x] = red[0];
}

__global__ __launch_bounds__(64) void scanB(int* partial) {
    int t = threadIdx.x;
    int v = (t < 40) ? partial[t] : 0;
    int orig = v;
    for (int off = 1; off < 64; off <<= 1) {
        int y = __shfl_up(v, off);
        if (t >= off) v += y;
    }
    if (t < 40) partial[t] = v - orig;  // exclusive
}

__global__ __launch_bounds__(512) void scanC(const int* __restrict__ cnt, const int* __restrict__ partial,
                                             int* row_ptr, int* cursor, int* colidx) {
    __shared__ int buf[512];
    int t = threadIdx.x;
    int n = blockIdx.x * 512 + t;
    int v = (n < N_NODES) ? cnt[n] : 0;
    int x = v;
    buf[t] = x; __syncthreads();
    for (int off = 1; off < 512; off <<= 1) {
        int y = (t >= off) ? buf[t - off] : 0;
        __syncthreads();
        x += y; buf[t] = x; __syncthreads();
    }
    int excl = partial[blockIdx.x] + x - v;
    if (n < N_NODES) {
        row_ptr[n] = excl;
        cursor[n] = excl + 1;     // self loop occupies slot 0
        colidx[excl] = n;         // self loop
    }
    if (n == 0) row_ptr[N_NODES] = E_EDGES + N_NODES;
}

__global__ __launch_bounds__(256) void fill_csr(const int* __restrict__ ei, int* cursor, int* colidx) {
    int e = blockIdx.x * 256 + threadIdx.x;
    if (e >= E_EDGES) return;
    int d = ei[E_EDGES + e];
    int s = ei[e];
    int pos = atomicAdd(&cursor[d], 1);
    colidx[pos] = s;
}

// ---------------- GEMM K=256 + fused attention-score dots ----------------
// BM=32 rows x 256 cols, 625 blocks (exact). 4 waves; wave owns 8 rows; lane owns 4 cols.

__global__ __launch_bounds__(256) void gemm256(const float* __restrict__ X,
                                               const float* __restrict__ W,
                                               const float* __restrict__ a_src,
                                               const float* __restrict__ a_dst,
                                               float* __restrict__ Hout,
                                               float* __restrict__ ssrc,
                                               float* __restrict__ sdst) {
    __shared__ float xs[32][36];
    int row0 = blockIdx.x * 32;
    int tid = threadIdx.x;
    int lane = tid & 63;
    int wave = tid >> 6;
    int c4 = lane * 4;
    int wrow = wave * 8;
    int lr = tid >> 3;   // 0..31 staging row
    int lf = tid & 7;    // 0..7 staging float4-slot

    float4 acc[8];
#pragma unroll
    for (int r = 0; r < 8; ++r) acc[r] = make_float4(0.f, 0.f, 0.f, 0.f);

    for (int k0 = 0; k0 < 256; k0 += 32) {
        __syncthreads();
        *reinterpret_cast<float4*>(&xs[lr][lf * 4]) =
            *reinterpret_cast<const float4*>(X + (size_t)(row0 + lr) * 256 + k0 + lf * 4);
        __syncthreads();
        for (int k = 0; k < 32; k += 4) {
            const float* wp = W + (size_t)(k0 + k) * HC + c4;
            float4 w0 = *reinterpret_cast<const float4*>(wp);
            float4 w1 = *reinterpret_cast<const float4*>(wp + HC);
            float4 w2 = *reinterpret_cast<const float4*>(wp + 2 * HC);
            float4 w3 = *reinterpret_cast<const float4*>(wp + 3 * HC);
#pragma unroll
            for (int r = 0; r < 8; ++r) {
                float4 xv = *reinterpret_cast<const float4*>(&xs[wrow + r][k]);
                acc[r].x += xv.x * w0.x; acc[r].y += xv.x * w0.y; acc[r].z += xv.x * w0.z; acc[r].w += xv.x * w0.w;
                acc[r].x += xv.y * w1.x; acc[r].y += xv.y * w1.y; acc[r].z += xv.y * w1.z; acc[r].w += xv.y * w1.w;
                acc[r].x += xv.z * w2.x; acc[r].y += xv.z * w2.y; acc[r].z += xv.z * w2.z; acc[r].w += xv.z * w2.w;
                acc[r].x += xv.w * w3.x; acc[r].y += xv.w * w3.y; acc[r].z += xv.w * w3.z; acc[r].w += xv.w * w3.w;
            }
        }
    }
    const float4 asv = *reinterpret_cast<const float4*>(a_src + c4);
    const float4 adv = *reinterpret_cast<const float4*>(a_dst + c4);
#pragma unroll
    for (int r = 0; r < 8; ++r) {
        int gr = row0 + wrow + r;
        *reinterpret_cast<float4*>(Hout + (size_t)gr * HC + c4) = acc[r];
        float ps = acc[r].x * asv.x + acc[r].y * asv.y + acc[r].z * asv.z + acc[r].w * asv.w;
        float pd = acc[r].x * adv.x + acc[r].y * adv.y + acc[r].z * adv.z + acc[r].w * adv.w;
        ps += __shfl_xor(ps, 1); pd += __shfl_xor(pd, 1);
        ps += __shfl_xor(ps, 2); pd += __shfl_xor(pd, 2);
        ps += __shfl_xor(ps, 4); pd += __shfl_xor(pd, 4);
        if ((lane & 7) == 0) {
            ssrc[gr * NH + (lane >> 3)] = ps;
            sdst[gr * NH + (lane >> 3)] = pd;
        }
    }
}

// ---------------- GEMM K=41 + fused attention-score dots ----------------

__global__ __launch_bounds__(256) void gemm41(const float* __restrict__ X,
                                              const float* __restrict__ W,
                                              const float* __restrict__ a_src,
                                              const float* __restrict__ a_dst,
                                              float* __restrict__ Hout,
                                              float* __restrict__ ssrc,
                                              float* __restrict__ sdst) {
    __shared__ float xs[32][44];
    int row0 = blockIdx.x * 32;
    int tid = threadIdx.x;
    int lane = tid & 63;
    int wave = tid >> 6;
    int c4 = lane * 4;
    int wrow = wave * 8;

    for (int idx = tid; idx < 32 * FIN; idx += 256) {
        int r = idx / FIN, k = idx - r * FIN;
        xs[r][k] = X[(size_t)(row0 + r) * FIN + k];
    }
    __syncthreads();

    float4 acc[8];
#pragma unroll
    for (int r = 0; r < 8; ++r) acc[r] = make_float4(0.f, 0.f, 0.f, 0.f);

    for (int k = 0; k < FIN; ++k) {
        float4 w0 = *reinterpret_cast<const float4*>(W + (size_t)k * HC + c4);
#pragma unroll
        for (int r = 0; r < 8; ++r) {
            float xv = xs[wrow + r][k];
            acc[r].x += xv * w0.x; acc[r].y += xv * w0.y; acc[r].z += xv * w0.z; acc[r].w += xv * w0.w;
        }
    }
    const float4 asv = *reinterpret_cast<const float4*>(a_src + c4);
    const float4 adv = *reinterpret_cast<const float4*>(a_dst + c4);
#pragma unroll
    for (int r = 0; r < 8; ++r) {
        int gr = row0 + wrow + r;
        *reinterpret_cast<float4*>(Hout + (size_t)gr * HC + c4) = acc[r];
        float ps = acc[r].x * asv.x + acc[r].y * asv.y + acc[r].z * asv.z + acc[r].w * asv.w;
        float pd = acc[r].x * adv.x + acc[r].y * adv.y + acc[r].z * adv.z + acc[r].w * adv.w;
        ps += __shfl_xor(ps, 1); pd += __shfl_xor(pd, 1);
        ps += __shfl_xor(ps, 2); pd += __shfl_xor(pd, 2);
        ps += __shfl_xor(ps, 4); pd += __shfl_xor(pd, 4);
        if ((lane & 7) == 0) {
            ssrc[gr * NH + (lane >> 3)] = ps;
            sdst[gr * NH + (lane >> 3)] = pd;
        }
    }
}

// ---------------- fused GAT aggregation + bias + BN(eval) + ELU ----------------
// one wave per dst node; lane owns channels [lane*4, lane*4+4); phase-2 unrolled x4
// for 4 independent gather chains per wave (latency-bound loop).

__global__ __launch_bounds__(256) void gat_agg(const int* __restrict__ row_ptr,
                                               const int* __restrict__ colidx,
                                               const float* __restrict__ ssrc,
                                               const float* __restrict__ sdst,
                                               const float* __restrict__ h,
                                               const float* __restrict__ bias,
                                               const float* __restrict__ gamma,
                                               const float* __restrict__ beta,
                                               float* __restrict__ out) {
    int wave = (blockIdx.x * blockDim.x + threadIdx.x) >> 6;
    int lane = threadIdx.x & 63;
    if (wave >= N_NODES) return;
    int n = wave;
    int beg = row_ptr[n], end = row_ptr[n + 1];
    int deg = end - beg;

    int hd1 = lane & 7;
    float sd1 = sdst[n * NH + hd1];
    float mx = -3.0e38f;
    for (int i = (lane >> 3); i < deg; i += 8) {
        int s = colidx[beg + i];
        float v = ssrc[s * NH + hd1] + sd1;
        v = (v >= 0.f) ? v : 0.2f * v;
        mx = fmaxf(mx, v);
    }
    mx = fmaxf(mx, __shfl_xor(mx, 8));
    mx = fmaxf(mx, __shfl_xor(mx, 16));
    mx = fmaxf(mx, __shfl_xor(mx, 32));

    int hd2 = lane >> 3;
    float m2 = __shfl(mx, hd2);
    float sd2 = sdst[n * NH + hd2];
    int c = lane * 4;
    float acc0 = 0.f, acc1 = 0.f, acc2 = 0.f, acc3 = 0.f, denom = 0.f;

    int i = 0;
    for (; i + 4 <= deg; i += 4) {
        int s0 = colidx[beg + i];
        int s1 = colidx[beg + i + 1];
        int s2 = colidx[beg + i + 2];
        int s3 = colidx[beg + i + 3];
        float v0 = ssrc[s0 * NH + hd2] + sd2; v0 = (v0 >= 0.f) ? v0 : 0.2f * v0;
        float v1 = ssrc[s1 * NH + hd2] + sd2; v1 = (v1 >= 0.f) ? v1 : 0.2f * v1;
        float v2 = ssrc[s2 * NH + hd2] + sd2; v2 = (v2 >= 0.f) ? v2 : 0.2f * v2;
        float v3 = ssrc[s3 * NH + hd2] + sd2; v3 = (v3 >= 0.f) ? v3 : 0.2f * v3;
        float w0 = __expf(v0 - m2);
        float w1 = __expf(v1 - m2);
        float w2 = __expf(v2 - m2);
        float w3 = __expf(v3 - m2);
        const float4 h0 = *reinterpret_cast<const float4*>(h + (size_t)s0 * HC + c);
        const float4 h1 = *reinterpret_cast<const float4*>(h + (size_t)s1 * HC + c);
        const float4 h2 = *reinterpret_cast<const float4*>(h + (size_t)s2 * HC + c);
        const float4 h3 = *reinterpret_cast<const float4*>(h + (size_t)s3 * HC + c);
        denom += (w0 + w1) + (w2 + w3);
        acc0 += w0 * h0.x + w1 * h1.x + w2 * h2.x + w3 * h3.x;
        acc1 += w0 * h0.y + w1 * h1.y + w2 * h2.y + w3 * h3.y;
        acc2 += w0 * h0.z + w1 * h1.z + w2 * h2.z + w3 * h3.z;
        acc3 += w0 * h0.w + w1 * h1.w + w2 * h2.w + w3 * h3.w;
    }
    for (; i < deg; ++i) {
        int s = colidx[beg + i];
        float v = ssrc[s * NH + hd2] + sd2;
        v = (v >= 0.f) ? v : 0.2f * v;
        float wgt = __expf(v - m2);
        denom += wgt;
        const float4 hv = *reinterpret_cast<const float4*>(h + (size_t)s * HC + c);
        acc0 += wgt * hv.x; acc1 += wgt * hv.y; acc2 += wgt * hv.z; acc3 += wgt * hv.w;
    }
    float inv = 1.0f / denom;
    const float bninv = 0.99999500003749981f;  // 1/sqrt(1+1e-5)
    float vals[4] = {acc0, acc1, acc2, acc3};
    float4 o;
    float* po = &o.x;
#pragma unroll
    for (int j = 0; j < 4; ++j) {
        float v = vals[j] * inv + bias[c + j];
        v = v * (gamma[c + j] * bninv) + beta[c + j];
        v = (v > 0.f) ? v : (__expf(v) - 1.0f);
        po[j] = v;
    }
    *reinterpret_cast<float4*>(out + (size_t)n * HC + c) = o;
}

// ---------------- pooling ----------------

__global__ __launch_bounds__(256) void graph_ranges(const int* __restrict__ batch, int* gstart, int* gend) {
    int n = blockIdx.x * 256 + threadIdx.x;
    if (n >= N_NODES) return;
    int b = batch[n];
    if (n == 0) gstart[b] = 0;
    else {
        int pb = batch[n - 1];
        if (pb != b) { gstart[b] = n; gend[pb] = n; }
    }
    if (n == N_NODES - 1) gend[b] = N_NODES;
}

__global__ __launch_bounds__(256) void pool_partial(const float* __restrict__ h,
                                                    const int* __restrict__ gstart,
                                                    const int* __restrict__ gend,
                                                    float* __restrict__ psum,
                                                    float* __restrict__ pmax) {
    int g = blockIdx.x >> 4;
    int c = blockIdx.x & (PCHUNK - 1);
    int t = threadIdx.x;
    int s = gstart[g], e = gend[g];
    int len = e - s;
    int n0 = s + (int)(((long long)len * c) / PCHUNK);
    int n1 = s + (int)(((long long)len * (c + 1)) / PCHUNK);
    float sum = 0.f, mx = -3.0e38f;
    for (int n = n0; n < n1; ++n) {
        float v = h[(size_t)n * HC + t];
        sum += v;
        mx = fmaxf(mx, v);
    }
    psum[(size_t)(g * PCHUNK + c) * HC + t] = sum;
    pmax[(size_t)(g * PCHUNK + c) * HC + t] = mx;
}

// ---------------- MLP head (fused pool-finalize + 3 FC layers) ----------------

__global__ __launch_bounds__(256) void mlp(const float* __restrict__ psum,
                                           const float* __restrict__ pmax,
                                           const int* __restrict__ gstart,
                                           const int* __restrict__ gend,
                                           const float* __restrict__ gsz,
                                           const float* __restrict__ fc1w, const float* __restrict__ fc1b,
                                           const float* __restrict__ gf1, const float* __restrict__ bf1,
                                           const float* __restrict__ fc2w, const float* __restrict__ fc2b,
                                           const float* __restrict__ gf2, const float* __restrict__ bf2,
                                           const float* __restrict__ fc3w, const float* __restrict__ fc3b,
                                           float* __restrict__ out) {
    __shared__ float pr[514];
    __shared__ float zz1[4][64];
    __shared__ float z1[64];
    __shared__ float zz2[8][32];
    __shared__ float z2[32];
    int g = blockIdx.x;
    int t = threadIdx.x;
    const float bninv = 0.99999500003749981f;

    {
        float s = 0.f, m = -3.0e38f;
#pragma unroll
        for (int c = 0; c < PCHUNK; ++c) {
            s += psum[(size_t)(g * PCHUNK + c) * HC + t];
            m = fmaxf(m, pmax[(size_t)(g * PCHUNK + c) * HC + t]);
        }
        float cnt = (float)(gend[g] - gstart[g]);
        pr[t] = s / fmaxf(cnt, 1.f);
        pr[256 + t] = m;
        if (t < 2) pr[512 + t] = gsz[g * 2 + t];
    }
    __syncthreads();

    {
        int u = t & 63, sp = t >> 6;
        int k0 = (514 * sp) / 4, k1 = (514 * (sp + 1)) / 4;
        float a = 0.f;
        for (int k = k0; k < k1; ++k) a += pr[k] * fc1w[k * 64 + u];
        zz1[sp][u] = a;
    }
    __syncthreads();
    if (t < 64) {
        float a = zz1[0][t] + zz1[1][t] + zz1[2][t] + zz1[3][t] + fc1b[t];
        a = a * (gf1[t] * bninv) + bf1[t];
        z1[t] = fmaxf(a, 0.f);
    }
    __syncthreads();

    {
        int u = t & 31, sp = t >> 5;
        float b = 0.f;
#pragma unroll
        for (int k = sp * 8; k < sp * 8 + 8; ++k) b += z1[k] * fc2w[k * 32 + u];
        zz2[sp][u] = b;
    }
    __syncthreads();
    if (t < 32) {
        float b = 0.f;
#pragma unroll
        for (int sp = 0; sp < 8; ++sp) b += zz2[sp][t];
        b += fc2b[t];
        b = b * (gf2[t] * bninv) + bf2[t];
        z2[t] = fmaxf(b, 0.f);
    }
    __syncthreads();

    if (t < 2) {
        float c = 0.f;
#pragma unroll
        for (int k = 0; k < 32; ++k) c += z2[k] * fc3w[k * 2 + t];
        out[g * 2 + t] = c + fc3b[t];
    }
}

// ---------------- launch ----------------

extern "C" void kernel_launch(void* const* d_in, const int* in_sizes, int n_in,
                              void* d_out, int out_size, void* d_ws, size_t ws_size,
                              hipStream_t stream) {
    const float* x    = (const float*)d_in[0];
    const int*   ei   = (const int*)d_in[1];
    const int*   batch= (const int*)d_in[2];
    const float* gsz  = (const float*)d_in[3];
    const float* W1   = (const float*)d_in[4];
    const float* as1  = (const float*)d_in[5];
    const float* ad1  = (const float*)d_in[6];
    const float* b1   = (const float*)d_in[7];
    const float* g1   = (const float*)d_in[8];
    const float* be1  = (const float*)d_in[9];
    const float* W2   = (const float*)d_in[10];
    const float* as2  = (const float*)d_in[11];
    const float* ad2  = (const float*)d_in[12];
    const float* b2   = (const float*)d_in[13];
    const float* g2   = (const float*)d_in[14];
    const float* be2  = (const float*)d_in[15];
    const float* fc1w = (const float*)d_in[16];
    const float* fc1b = (const float*)d_in[17];
    const float* gf1  = (const float*)d_in[18];
    const float* bf1  = (const float*)d_in[19];
    const float* fc2w = (const float*)d_in[20];
    const float* fc2b = (const float*)d_in[21];
    const float* gf2  = (const float*)d_in[22];
    const float* bf2  = (const float*)d_in[23];
    const float* fc3w = (const float*)d_in[24];
    const float* fc3b = (const float*)d_in[25];
    float* out = (float*)d_out;

    char* w = (char*)d_ws;
    float* hbuf   = (float*)w; w += (size_t)N_NODES * HC * 4;
    float* actbuf = (float*)w; w += (size_t)N_NODES * HC * 4;
    float* ssrc   = (float*)w; w += (size_t)N_NODES * NH * 4;
    float* sdst   = (float*)w; w += (size_t)N_NODES * NH * 4;
    int* row_ptr  = (int*)w;   w += (size_t)(N_NODES + 1) * 4;
    int* cursor   = (int*)w;   w += (size_t)N_NODES * 4;
    int* cnt      = (int*)w;   w += (size_t)N_NODES * 4;
    int* colidx   = (int*)w;   w += (size_t)(E_EDGES + N_NODES) * 4;
    int* partial  = (int*)w;   w += 64 * 4;
    int* gstart   = (int*)w;   w += 64 * 4;
    int* gend     = (int*)w;   w += 64 * 4;

    // pool partials alias hbuf (dead after second gat_agg)
    float* psum = hbuf;
    float* pmax = hbuf + (size_t)NG * PCHUNK * HC;

    hipMemsetAsync(gstart, 0, 2 * 64 * 4, stream);

    init_counts<<<79, 256, 0, stream>>>(cnt);
    hist<<<1250, 256, 0, stream>>>(ei, cnt);
    scanA<<<40, 512, 0, stream>>>(cnt, partial);
    scanB<<<1, 64, 0, stream>>>(partial);
    scanC<<<40, 512, 0, stream>>>(cnt, partial, row_ptr, cursor, colidx);
    fill_csr<<<1250, 256, 0, stream>>>(ei, cursor, colidx);

    gemm41<<<625, 256, 0, stream>>>(x, W1, as1, ad1, hbuf, ssrc, sdst);
    gat_agg<<<5000, 256, 0, stream>>>(row_ptr, colidx, ssrc, sdst, hbuf, b1, g1, be1, actbuf);

    gemm256<<<625, 256, 0, stream>>>(actbuf, W2, as2, ad2, hbuf, ssrc, sdst);
    gat_agg<<<5000, 256, 0, stream>>>(row_ptr, colidx, ssrc, sdst, hbuf, b2, g2, be2, actbuf);

    graph_ranges<<<79, 256, 0, stream>>>(batch, gstart, gend);
    pool_partial<<<NG * PCHUNK, 256, 0, stream>>>(actbuf, gstart, gend, psum, pmax);
    mlp<<<NG, 256, 0, stream>>>(psum, pmax, gstart, gend, gsz,
                                fc1w, fc1b, gf1, bf1, fc2w, fc2b, gf2, bf2, fc3w, fc3b, out);
}

// Round 6
// 226.329 us; speedup vs baseline: 2.2458x; 1.1902x over previous
//
#include <hip/hip_runtime.h>
#include <hip/hip_bf16.h>

#define N_NODES 20000
#define E_EDGES 320000
#define NH 8
#define NC 32
#define HC 256
#define FIN 41
#define NG 64
#define PCHUNK 16

typedef _Float16 f16x4 __attribute__((ext_vector_type(4)));
typedef _Float16 f16x8 __attribute__((ext_vector_type(8)));
typedef float f32x4v __attribute__((ext_vector_type(4)));

// ---------------- CSR build ----------------

__global__ __launch_bounds__(256) void init_counts(int* cnt) {
    int n = blockIdx.x * 256 + threadIdx.x;
    if (n < N_NODES) cnt[n] = 1;  // self loop
}

__global__ __launch_bounds__(256) void hist(const int* __restrict__ ei, int* cnt) {
    int e = blockIdx.x * 256 + threadIdx.x;
    if (e < E_EDGES) atomicAdd(&cnt[ei[E_EDGES + e]], 1);
}

__global__ __launch_bounds__(512) void scanA(const int* __restrict__ cnt, int* partial) {
    __shared__ int red[512];
    int n = blockIdx.x * 512 + threadIdx.x;
    int v = (n < N_NODES) ? cnt[n] : 0;
    red[threadIdx.x] = v; __syncthreads();
    for (int off = 256; off > 0; off >>= 1) {
        if (threadIdx.x < off) red[threadIdx.x] += red[threadIdx.x + off];
        __syncthreads();
    }
    if (threadIdx.x == 0) partial[blockIdx.x] = red[0];
}

__global__ __launch_bounds__(64) void scanB(int* partial) {
    int t = threadIdx.x;
    int v = (t < 40) ? partial[t] : 0;
    int orig = v;
    for (int off = 1; off < 64; off <<= 1) {
        int y = __shfl_up(v, off);
        if (t >= off) v += y;
    }
    if (t < 40) partial[t] = v - orig;  // exclusive
}

__global__ __launch_bounds__(512) void scanC(const int* __restrict__ cnt, const int* __restrict__ partial,
                                             int* row_ptr, int* cursor, int* colidx) {
    __shared__ int buf[512];
    int t = threadIdx.x;
    int n = blockIdx.x * 512 + t;
    int v = (n < N_NODES) ? cnt[n] : 0;
    int x = v;
    buf[t] = x; __syncthreads();
    for (int off = 1; off < 512; off <<= 1) {
        int y = (t >= off) ? buf[t - off] : 0;
        __syncthreads();
        x += y; buf[t] = x; __syncthreads();
    }
    int excl = partial[blockIdx.x] + x - v;
    if (n < N_NODES) {
        row_ptr[n] = excl;
        cursor[n] = excl + 1;     // self loop occupies slot 0
        colidx[excl] = n;         // self loop
    }
    if (n == 0) row_ptr[N_NODES] = E_EDGES + N_NODES;
}

__global__ __launch_bounds__(256) void fill_csr(const int* __restrict__ ei, int* cursor, int* colidx) {
    int e = blockIdx.x * 256 + threadIdx.x;
    if (e >= E_EDGES) return;
    int d = ei[E_EDGES + e];
    int s = ei[e];
    int pos = atomicAdd(&cursor[d], 1);
    colidx[pos] = s;
}

// ---------------- W2 -> fp16 col-major (Wt[n][k] = W2[k][n]) ----------------

__global__ __launch_bounds__(256) void wconv(const float* __restrict__ W, _Float16* __restrict__ Wt) {
    int n = blockIdx.x, k = threadIdx.x;
    Wt[n * 256 + k] = (_Float16)W[k * 256 + n];
}

// ---------------- GEMM K=256 via MFMA fp16 + fused score dots ----------------
// block = 32 rows x 256 cols, 4 waves; wave w: cols [w*64, w*64+64) = heads 2w,2w+1.
// wave computes 2x4 tiles of 16x16 via v_mfma_f32_16x16x16f16, K-steps of 16.
// A: lane holds X[row0+(l&15)][k0+4*(l>>4)+j]; B: Wt[col][k] same k-mapping.
// D: col=l&15, row=4*(l>>4)+r (m89-verified, dtype-independent).

__global__ __launch_bounds__(256) void gemm256h(const _Float16* __restrict__ Xh,
                                                const _Float16* __restrict__ Wt,
                                                const float* __restrict__ a_src,
                                                const float* __restrict__ a_dst,
                                                _Float16* __restrict__ Hh,
                                                float* __restrict__ ssrc,
                                                float* __restrict__ sdst) {
    __shared__ _Float16 hs[32 * 264];
    int row0 = blockIdx.x * 32;
    int tid = threadIdx.x;
    int lane = tid & 63;
    int w = tid >> 6;
    int r16 = lane & 15;
    int kseg = lane >> 4;

    f32x4v acc[2][4];
#pragma unroll
    for (int a = 0; a < 2; ++a)
#pragma unroll
        for (int b = 0; b < 4; ++b) acc[a][b] = (f32x4v){0.f, 0.f, 0.f, 0.f};

    const _Float16* XA = Xh + (size_t)(row0 + r16) * 256 + kseg * 4;
    const _Float16* WB = Wt + (size_t)(w * 64 + r16) * 256 + kseg * 4;

    for (int k0 = 0; k0 < 256; k0 += 16) {
        f16x4 a0 = *(const f16x4*)(XA + k0);
        f16x4 a1 = *(const f16x4*)(XA + 16 * 256 + k0);
        f16x4 b0 = *(const f16x4*)(WB + k0);
        f16x4 b1 = *(const f16x4*)(WB + 16 * 256 + k0);
        f16x4 b2 = *(const f16x4*)(WB + 32 * 256 + k0);
        f16x4 b3 = *(const f16x4*)(WB + 48 * 256 + k0);
        acc[0][0] = __builtin_amdgcn_mfma_f32_16x16x16f16(a0, b0, acc[0][0], 0, 0, 0);
        acc[0][1] = __builtin_amdgcn_mfma_f32_16x16x16f16(a0, b1, acc[0][1], 0, 0, 0);
        acc[0][2] = __builtin_amdgcn_mfma_f32_16x16x16f16(a0, b2, acc[0][2], 0, 0, 0);
        acc[0][3] = __builtin_amdgcn_mfma_f32_16x16x16f16(a0, b3, acc[0][3], 0, 0, 0);
        acc[1][0] = __builtin_amdgcn_mfma_f32_16x16x16f16(a1, b0, acc[1][0], 0, 0, 0);
        acc[1][1] = __builtin_amdgcn_mfma_f32_16x16x16f16(a1, b1, acc[1][1], 0, 0, 0);
        acc[1][2] = __builtin_amdgcn_mfma_f32_16x16x16f16(a1, b2, acc[1][2], 0, 0, 0);
        acc[1][3] = __builtin_amdgcn_mfma_f32_16x16x16f16(a1, b3, acc[1][3], 0, 0, 0);
    }

    // fused attention-score dots: wave w's 64 cols = heads 2w, 2w+1 complete
    float as0 = a_src[w * 64 + r16],      as1 = a_src[w * 64 + 16 + r16];
    float as2 = a_src[w * 64 + 32 + r16], as3 = a_src[w * 64 + 48 + r16];
    float ad0 = a_dst[w * 64 + r16],      ad1 = a_dst[w * 64 + 16 + r16];
    float ad2 = a_dst[w * 64 + 32 + r16], ad3 = a_dst[w * 64 + 48 + r16];
#pragma unroll
    for (int tm = 0; tm < 2; ++tm) {
#pragma unroll
        for (int r = 0; r < 4; ++r) {
            float p0 = acc[tm][0][r] * as0 + acc[tm][1][r] * as1;
            float p1 = acc[tm][2][r] * as2 + acc[tm][3][r] * as3;
            float q0 = acc[tm][0][r] * ad0 + acc[tm][1][r] * ad1;
            float q1 = acc[tm][2][r] * ad2 + acc[tm][3][r] * ad3;
#pragma unroll
            for (int m = 1; m < 16; m <<= 1) {
                p0 += __shfl_xor(p0, m); p1 += __shfl_xor(p1, m);
                q0 += __shfl_xor(q0, m); q1 += __shfl_xor(q1, m);
            }
            if (r16 == 0) {
                int row = row0 + tm * 16 + kseg * 4 + r;
                ssrc[row * NH + w * 2]     = p0;
                ssrc[row * NH + w * 2 + 1] = p1;
                sdst[row * NH + w * 2]     = q0;
                sdst[row * NH + w * 2 + 1] = q1;
            }
        }
    }

    // H (fp16) via LDS transpose for coalesced 16B stores
#pragma unroll
    for (int tm = 0; tm < 2; ++tm)
#pragma unroll
        for (int tn = 0; tn < 4; ++tn)
#pragma unroll
            for (int r = 0; r < 4; ++r)
                hs[(tm * 16 + kseg * 4 + r) * 264 + w * 64 + tn * 16 + r16] = (_Float16)acc[tm][tn][r];
    __syncthreads();
#pragma unroll
    for (int i = 0; i < 4; ++i) {
        int idx = i * 256 + tid;
        int rr = idx >> 5;
        int cc = idx & 31;
        f16x8 v = *(const f16x8*)&hs[rr * 264 + cc * 8];
        *(f16x8*)(Hh + (size_t)(row0 + rr) * 256 + cc * 8) = v;
    }
}

// ---------------- GEMM K=41 (fp32 VALU) + fused score dots, fp16 H out ----------------

__global__ __launch_bounds__(256) void gemm41(const float* __restrict__ X,
                                              const float* __restrict__ W,
                                              const float* __restrict__ a_src,
                                              const float* __restrict__ a_dst,
                                              _Float16* __restrict__ Hh,
                                              float* __restrict__ ssrc,
                                              float* __restrict__ sdst) {
    __shared__ float xs[32][44];
    int row0 = blockIdx.x * 32;
    int tid = threadIdx.x;
    int lane = tid & 63;
    int wave = tid >> 6;
    int c4 = lane * 4;
    int wrow = wave * 8;

    for (int idx = tid; idx < 32 * FIN; idx += 256) {
        int r = idx / FIN, k = idx - r * FIN;
        xs[r][k] = X[(size_t)(row0 + r) * FIN + k];
    }
    __syncthreads();

    float4 acc[8];
#pragma unroll
    for (int r = 0; r < 8; ++r) acc[r] = make_float4(0.f, 0.f, 0.f, 0.f);

    for (int k = 0; k < FIN; ++k) {
        float4 w0 = *reinterpret_cast<const float4*>(W + (size_t)k * HC + c4);
#pragma unroll
        for (int r = 0; r < 8; ++r) {
            float xv = xs[wrow + r][k];
            acc[r].x += xv * w0.x; acc[r].y += xv * w0.y; acc[r].z += xv * w0.z; acc[r].w += xv * w0.w;
        }
    }
    const float4 asv = *reinterpret_cast<const float4*>(a_src + c4);
    const float4 adv = *reinterpret_cast<const float4*>(a_dst + c4);
#pragma unroll
    for (int r = 0; r < 8; ++r) {
        int gr = row0 + wrow + r;
        f16x4 hv;
        hv[0] = (_Float16)acc[r].x; hv[1] = (_Float16)acc[r].y;
        hv[2] = (_Float16)acc[r].z; hv[3] = (_Float16)acc[r].w;
        *(f16x4*)(Hh + (size_t)gr * HC + c4) = hv;
        float ps = acc[r].x * asv.x + acc[r].y * asv.y + acc[r].z * asv.z + acc[r].w * asv.w;
        float pd = acc[r].x * adv.x + acc[r].y * adv.y + acc[r].z * adv.z + acc[r].w * adv.w;
        ps += __shfl_xor(ps, 1); pd += __shfl_xor(pd, 1);
        ps += __shfl_xor(ps, 2); pd += __shfl_xor(pd, 2);
        ps += __shfl_xor(ps, 4); pd += __shfl_xor(pd, 4);
        if ((lane & 7) == 0) {
            ssrc[gr * NH + (lane >> 3)] = ps;
            sdst[gr * NH + (lane >> 3)] = pd;
        }
    }
}

// ---------------- fused GAT aggregation + bias + BN(eval) + ELU ----------------
// h gathered as fp16 (half traffic). OUTH=1: fp16 out (layer1), else fp32 (layer2).

template <int OUTH>
__global__ __launch_bounds__(256) void gat_agg(const int* __restrict__ row_ptr,
                                               const int* __restrict__ colidx,
                                               const float* __restrict__ ssrc,
                                               const float* __restrict__ sdst,
                                               const _Float16* __restrict__ h,
                                               const float* __restrict__ bias,
                                               const float* __restrict__ gamma,
                                               const float* __restrict__ beta,
                                               float* __restrict__ out,
                                               _Float16* __restrict__ outh) {
    int wave = (blockIdx.x * blockDim.x + threadIdx.x) >> 6;
    int lane = threadIdx.x & 63;
    if (wave >= N_NODES) return;
    int n = wave;
    int beg = row_ptr[n], end = row_ptr[n + 1];
    int deg = end - beg;

    int hd1 = lane & 7;
    float sd1 = sdst[n * NH + hd1];
    float mx = -3.0e38f;
    for (int i = (lane >> 3); i < deg; i += 8) {
        int s = colidx[beg + i];
        float v = ssrc[s * NH + hd1] + sd1;
        v = (v >= 0.f) ? v : 0.2f * v;
        mx = fmaxf(mx, v);
    }
    mx = fmaxf(mx, __shfl_xor(mx, 8));
    mx = fmaxf(mx, __shfl_xor(mx, 16));
    mx = fmaxf(mx, __shfl_xor(mx, 32));

    int hd2 = lane >> 3;
    float m2 = __shfl(mx, hd2);
    float sd2 = sdst[n * NH + hd2];
    int c = lane * 4;
    float acc0 = 0.f, acc1 = 0.f, acc2 = 0.f, acc3 = 0.f, denom = 0.f;

    int i = 0;
    for (; i + 4 <= deg; i += 4) {
        int s0 = colidx[beg + i];
        int s1 = colidx[beg + i + 1];
        int s2 = colidx[beg + i + 2];
        int s3 = colidx[beg + i + 3];
        float v0 = ssrc[s0 * NH + hd2] + sd2; v0 = (v0 >= 0.f) ? v0 : 0.2f * v0;
        float v1 = ssrc[s1 * NH + hd2] + sd2; v1 = (v1 >= 0.f) ? v1 : 0.2f * v1;
        float v2 = ssrc[s2 * NH + hd2] + sd2; v2 = (v2 >= 0.f) ? v2 : 0.2f * v2;
        float v3 = ssrc[s3 * NH + hd2] + sd2; v3 = (v3 >= 0.f) ? v3 : 0.2f * v3;
        float w0 = __expf(v0 - m2);
        float w1 = __expf(v1 - m2);
        float w2 = __expf(v2 - m2);
        float w3 = __expf(v3 - m2);
        const f16x4 h0 = *reinterpret_cast<const f16x4*>(h + (size_t)s0 * HC + c);
        const f16x4 h1 = *reinterpret_cast<const f16x4*>(h + (size_t)s1 * HC + c);
        const f16x4 h2 = *reinterpret_cast<const f16x4*>(h + (size_t)s2 * HC + c);
        const f16x4 h3 = *reinterpret_cast<const f16x4*>(h + (size_t)s3 * HC + c);
        denom += (w0 + w1) + (w2 + w3);
        acc0 += w0 * (float)h0[0] + w1 * (float)h1[0] + w2 * (float)h2[0] + w3 * (float)h3[0];
        acc1 += w0 * (float)h0[1] + w1 * (float)h1[1] + w2 * (float)h2[1] + w3 * (float)h3[1];
        acc2 += w0 * (float)h0[2] + w1 * (float)h1[2] + w2 * (float)h2[2] + w3 * (float)h3[2];
        acc3 += w0 * (float)h0[3] + w1 * (float)h1[3] + w2 * (float)h2[3] + w3 * (float)h3[3];
    }
    for (; i < deg; ++i) {
        int s = colidx[beg + i];
        float v = ssrc[s * NH + hd2] + sd2;
        v = (v >= 0.f) ? v : 0.2f * v;
        float wgt = __expf(v - m2);
        denom += wgt;
        const f16x4 hv = *reinterpret_cast<const f16x4*>(h + (size_t)s * HC + c);
        acc0 += wgt * (float)hv[0]; acc1 += wgt * (float)hv[1];
        acc2 += wgt * (float)hv[2]; acc3 += wgt * (float)hv[3];
    }
    float inv = 1.0f / denom;
    const float bninv = 0.99999500003749981f;  // 1/sqrt(1+1e-5)
    float vals[4] = {acc0, acc1, acc2, acc3};
    float res[4];
#pragma unroll
    for (int j = 0; j < 4; ++j) {
        float v = vals[j] * inv + bias[c + j];
        v = v * (gamma[c + j] * bninv) + beta[c + j];
        v = (v > 0.f) ? v : (__expf(v) - 1.0f);
        res[j] = v;
    }
    if (OUTH) {
        f16x4 o;
        o[0] = (_Float16)res[0]; o[1] = (_Float16)res[1];
        o[2] = (_Float16)res[2]; o[3] = (_Float16)res[3];
        *(f16x4*)(outh + (size_t)n * HC + c) = o;
    } else {
        float4 o = make_float4(res[0], res[1], res[2], res[3]);
        *reinterpret_cast<float4*>(out + (size_t)n * HC + c) = o;
    }
}

// ---------------- pooling ----------------

__global__ __launch_bounds__(256) void graph_ranges(const int* __restrict__ batch, int* gstart, int* gend) {
    int n = blockIdx.x * 256 + threadIdx.x;
    if (n >= N_NODES) return;
    int b = batch[n];
    if (n == 0) gstart[b] = 0;
    else {
        int pb = batch[n - 1];
        if (pb != b) { gstart[b] = n; gend[pb] = n; }
    }
    if (n == N_NODES - 1) gend[b] = N_NODES;
}

__global__ __launch_bounds__(256) void pool_partial(const float* __restrict__ h,
                                                    const int* __restrict__ gstart,
                                                    const int* __restrict__ gend,
                                                    float* __restrict__ psum,
                                                    float* __restrict__ pmax) {
    int g = blockIdx.x >> 4;
    int c = blockIdx.x & (PCHUNK - 1);
    int t = threadIdx.x;
    int s = gstart[g], e = gend[g];
    int len = e - s;
    int n0 = s + (int)(((long long)len * c) / PCHUNK);
    int n1 = s + (int)(((long long)len * (c + 1)) / PCHUNK);
    float sum = 0.f, mx = -3.0e38f;
    for (int n = n0; n < n1; ++n) {
        float v = h[(size_t)n * HC + t];
        sum += v;
        mx = fmaxf(mx, v);
    }
    psum[(size_t)(g * PCHUNK + c) * HC + t] = sum;
    pmax[(size_t)(g * PCHUNK + c) * HC + t] = mx;
}

// ---------------- MLP head (fused pool-finalize + 3 FC layers) ----------------

__global__ __launch_bounds__(256) void mlp(const float* __restrict__ psum,
                                           const float* __restrict__ pmax,
                                           const int* __restrict__ gstart,
                                           const int* __restrict__ gend,
                                           const float* __restrict__ gsz,
                                           const float* __restrict__ fc1w, const float* __restrict__ fc1b,
                                           const float* __restrict__ gf1, const float* __restrict__ bf1,
                                           const float* __restrict__ fc2w, const float* __restrict__ fc2b,
                                           const float* __restrict__ gf2, const float* __restrict__ bf2,
                                           const float* __restrict__ fc3w, const float* __restrict__ fc3b,
                                           float* __restrict__ out) {
    __shared__ float pr[514];
    __shared__ float zz1[4][64];
    __shared__ float z1[64];
    __shared__ float zz2[8][32];
    __shared__ float z2[32];
    int g = blockIdx.x;
    int t = threadIdx.x;
    const float bninv = 0.99999500003749981f;

    {
        float s = 0.f, m = -3.0e38f;
#pragma unroll
        for (int c = 0; c < PCHUNK; ++c) {
            s += psum[(size_t)(g * PCHUNK + c) * HC + t];
            m = fmaxf(m, pmax[(size_t)(g * PCHUNK + c) * HC + t]);
        }
        float cnt = (float)(gend[g] - gstart[g]);
        pr[t] = s / fmaxf(cnt, 1.f);
        pr[256 + t] = m;
        if (t < 2) pr[512 + t] = gsz[g * 2 + t];
    }
    __syncthreads();

    {
        int u = t & 63, sp = t >> 6;
        int k0 = (514 * sp) / 4, k1 = (514 * (sp + 1)) / 4;
        float a = 0.f;
        for (int k = k0; k < k1; ++k) a += pr[k] * fc1w[k * 64 + u];
        zz1[sp][u] = a;
    }
    __syncthreads();
    if (t < 64) {
        float a = zz1[0][t] + zz1[1][t] + zz1[2][t] + zz1[3][t] + fc1b[t];
        a = a * (gf1[t] * bninv) + bf1[t];
        z1[t] = fmaxf(a, 0.f);
    }
    __syncthreads();

    {
        int u = t & 31, sp = t >> 5;
        float b = 0.f;
#pragma unroll
        for (int k = sp * 8; k < sp * 8 + 8; ++k) b += z1[k] * fc2w[k * 32 + u];
        zz2[sp][u] = b;
    }
    __syncthreads();
    if (t < 32) {
        float b = 0.f;
#pragma unroll
        for (int sp = 0; sp < 8; ++sp) b += zz2[sp][t];
        b += fc2b[t];
        b = b * (gf2[t] * bninv) + bf2[t];
        z2[t] = fmaxf(b, 0.f);
    }
    __syncthreads();

    if (t < 2) {
        float c = 0.f;
#pragma unroll
        for (int k = 0; k < 32; ++k) c += z2[k] * fc3w[k * 2 + t];
        out[g * 2 + t] = c + fc3b[t];
    }
}

// ---------------- launch ----------------

extern "C" void kernel_launch(void* const* d_in, const int* in_sizes, int n_in,
                              void* d_out, int out_size, void* d_ws, size_t ws_size,
                              hipStream_t stream) {
    const float* x    = (const float*)d_in[0];
    const int*   ei   = (const int*)d_in[1];
    const int*   batch= (const int*)d_in[2];
    const float* gsz  = (const float*)d_in[3];
    const float* W1   = (const float*)d_in[4];
    const float* as1  = (const float*)d_in[5];
    const float* ad1  = (const float*)d_in[6];
    const float* b1   = (const float*)d_in[7];
    const float* g1   = (const float*)d_in[8];
    const float* be1  = (const float*)d_in[9];
    const float* W2   = (const float*)d_in[10];
    const float* as2  = (const float*)d_in[11];
    const float* ad2  = (const float*)d_in[12];
    const float* b2   = (const float*)d_in[13];
    const float* g2   = (const float*)d_in[14];
    const float* be2  = (const float*)d_in[15];
    const float* fc1w = (const float*)d_in[16];
    const float* fc1b = (const float*)d_in[17];
    const float* gf1  = (const float*)d_in[18];
    const float* bf1  = (const float*)d_in[19];
    const float* fc2w = (const float*)d_in[20];
    const float* fc2b = (const float*)d_in[21];
    const float* gf2  = (const float*)d_in[22];
    const float* bf2  = (const float*)d_in[23];
    const float* fc3w = (const float*)d_in[24];
    const float* fc3b = (const float*)d_in[25];
    float* out = (float*)d_out;

    char* w = (char*)d_ws;
    _Float16* h_half   = (_Float16*)w; w += (size_t)N_NODES * HC * 2;   // 10.24 MB
    _Float16* act_half = (_Float16*)w; w += (size_t)N_NODES * HC * 2;   // 10.24 MB
    float* actbuf      = (float*)w;    w += (size_t)N_NODES * HC * 4;   // 20.48 MB (pool in)
    _Float16* Wt       = (_Float16*)w; w += (size_t)HC * HC * 2;        // 128 KB
    float* ssrc        = (float*)w;    w += (size_t)N_NODES * NH * 4;
    float* sdst        = (float*)w;    w += (size_t)N_NODES * NH * 4;
    int* row_ptr  = (int*)w;   w += (size_t)(N_NODES + 1) * 4;
    int* cursor   = (int*)w;   w += (size_t)N_NODES * 4;
    int* cnt      = (int*)w;   w += (size_t)N_NODES * 4;
    int* colidx   = (int*)w;   w += (size_t)(E_EDGES + N_NODES) * 4;
    int* partial  = (int*)w;   w += 64 * 4;
    int* gstart   = (int*)w;   w += 64 * 4;
    int* gend     = (int*)w;   w += 64 * 4;

    // pool partials alias h_half (dead after gat_agg#2)
    float* psum = (float*)h_half;
    float* pmax = psum + (size_t)NG * PCHUNK * HC;

    hipMemsetAsync(gstart, 0, 2 * 64 * 4, stream);

    init_counts<<<79, 256, 0, stream>>>(cnt);
    hist<<<1250, 256, 0, stream>>>(ei, cnt);
    scanA<<<40, 512, 0, stream>>>(cnt, partial);
    scanB<<<1, 64, 0, stream>>>(partial);
    scanC<<<40, 512, 0, stream>>>(cnt, partial, row_ptr, cursor, colidx);
    fill_csr<<<1250, 256, 0, stream>>>(ei, cursor, colidx);
    wconv<<<256, 256, 0, stream>>>(W2, Wt);

    gemm41<<<625, 256, 0, stream>>>(x, W1, as1, ad1, h_half, ssrc, sdst);
    gat_agg<1><<<5000, 256, 0, stream>>>(row_ptr, colidx, ssrc, sdst, h_half, b1, g1, be1,
                                         (float*)nullptr, act_half);

    gemm256h<<<625, 256, 0, stream>>>(act_half, Wt, as2, ad2, h_half, ssrc, sdst);
    gat_agg<0><<<5000, 256, 0, stream>>>(row_ptr, colidx, ssrc, sdst, h_half, b2, g2, be2,
                                         actbuf, (_Float16*)nullptr);

    graph_ranges<<<79, 256, 0, stream>>>(batch, gstart, gend);
    pool_partial<<<NG * PCHUNK, 256, 0, stream>>>(actbuf, gstart, gend, psum, pmax);
    mlp<<<NG, 256, 0, stream>>>(psum, pmax, gstart, gend, gsz,
                                fc1w, fc1b, gf1, bf1, fc2w, fc2b, gf2, bf2, fc3w, fc3b, out);
}

// Round 7
// 207.744 us; speedup vs baseline: 2.4467x; 1.0895x over previous
//
#include <hip/hip_runtime.h>
#include <hip/hip_bf16.h>

#define N_NODES 20000
#define E_EDGES 320000
#define NH 8
#define NC 32
#define HC 256
#define FIN 41
#define NG 64
#define PCHUNK 16

typedef _Float16 f16x4 __attribute__((ext_vector_type(4)));
typedef _Float16 f16x8 __attribute__((ext_vector_type(8)));
typedef float f32x4v __attribute__((ext_vector_type(4)));

// ---------------- CSR build ----------------

__global__ __launch_bounds__(256) void init_counts(int* cnt) {
    int n = blockIdx.x * 256 + threadIdx.x;
    if (n < N_NODES) cnt[n] = 1;  // self loop
}

__global__ __launch_bounds__(256) void hist(const int* __restrict__ ei, int* cnt) {
    int e = blockIdx.x * 256 + threadIdx.x;
    if (e < E_EDGES) atomicAdd(&cnt[ei[E_EDGES + e]], 1);
}

__global__ __launch_bounds__(512) void scanA(const int* __restrict__ cnt, int* partial) {
    __shared__ int red[512];
    int n = blockIdx.x * 512 + threadIdx.x;
    int v = (n < N_NODES) ? cnt[n] : 0;
    red[threadIdx.x] = v; __syncthreads();
    for (int off = 256; off > 0; off >>= 1) {
        if (threadIdx.x < off) red[threadIdx.x] += red[threadIdx.x + off];
        __syncthreads();
    }
    if (threadIdx.x == 0) partial[blockIdx.x] = red[0];
}

__global__ __launch_bounds__(64) void scanB(int* partial) {
    int t = threadIdx.x;
    int v = (t < 40) ? partial[t] : 0;
    int orig = v;
    for (int off = 1; off < 64; off <<= 1) {
        int y = __shfl_up(v, off);
        if (t >= off) v += y;
    }
    if (t < 40) partial[t] = v - orig;  // exclusive
}

__global__ __launch_bounds__(512) void scanC(const int* __restrict__ cnt, const int* __restrict__ partial,
                                             int* row_ptr, int* cursor, int* colidx) {
    __shared__ int buf[512];
    int t = threadIdx.x;
    int n = blockIdx.x * 512 + t;
    int v = (n < N_NODES) ? cnt[n] : 0;
    int x = v;
    buf[t] = x; __syncthreads();
    for (int off = 1; off < 512; off <<= 1) {
        int y = (t >= off) ? buf[t - off] : 0;
        __syncthreads();
        x += y; buf[t] = x; __syncthreads();
    }
    int excl = partial[blockIdx.x] + x - v;
    if (n < N_NODES) {
        row_ptr[n] = excl;
        cursor[n] = excl + 1;     // self loop occupies slot 0
        colidx[excl] = n;         // self loop
    }
    if (n == 0) row_ptr[N_NODES] = E_EDGES + N_NODES;
}

__global__ __launch_bounds__(256) void fill_csr(const int* __restrict__ ei, int* cursor, int* colidx) {
    int e = blockIdx.x * 256 + threadIdx.x;
    if (e >= E_EDGES) return;
    int d = ei[E_EDGES + e];
    int s = ei[e];
    int pos = atomicAdd(&cursor[d], 1);
    colidx[pos] = s;
}

// ---------------- W2 -> fp16 col-major via LDS tile transpose ----------------
// grid 16 = 4x4 tiles of 64x64. Wt[n][k] = W2[k][n].

__global__ __launch_bounds__(256) void wconv(const float* __restrict__ W, _Float16* __restrict__ Wt) {
    __shared__ float tile[64][65];
    int tr = (blockIdx.x >> 2) * 64;   // k-range
    int tc = (blockIdx.x & 3) * 64;    // n-range
    int t = threadIdx.x;
    int rr = t >> 6, cc = t & 63;
#pragma unroll
    for (int j = 0; j < 16; ++j) {
        int row = j * 4 + rr;
        tile[row][cc] = W[(size_t)(tr + row) * 256 + tc + cc];
    }
    __syncthreads();
#pragma unroll
    for (int j = 0; j < 16; ++j) {
        int row = j * 4 + rr;  // n-offset
        Wt[(size_t)(tc + row) * 256 + tr + cc] = (_Float16)tile[cc][row];
    }
}

// ---------------- fc1w [514][64] -> fc1wT [64][520] (row-padded) ----------------

__global__ __launch_bounds__(256) void fc1conv(const float* __restrict__ fc1w, float* __restrict__ fc1wT) {
    int id = blockIdx.x * 256 + threadIdx.x;
    if (id >= 64 * 514) return;
    int u = id / 514, kk = id - u * 514;
    fc1wT[u * 520 + kk] = fc1w[kk * 64 + u];
}

// ---------------- GEMM K=256 via MFMA fp16 + fused score dots ----------------
// block = 32 rows x 256 cols, 4 waves; wave w: cols [w*64, w*64+64) = heads 2w,2w+1.
// 2-deep register pipeline over fully-unrolled 16 K-steps.

__global__ __launch_bounds__(256) void gemm256h(const _Float16* __restrict__ Xh,
                                                const _Float16* __restrict__ Wt,
                                                const float* __restrict__ a_src,
                                                const float* __restrict__ a_dst,
                                                _Float16* __restrict__ Hh,
                                                float* __restrict__ ssrc,
                                                float* __restrict__ sdst) {
    __shared__ _Float16 hs[32 * 264];
    int row0 = blockIdx.x * 32;
    int tid = threadIdx.x;
    int lane = tid & 63;
    int w = tid >> 6;
    int r16 = lane & 15;
    int kseg = lane >> 4;

    f32x4v acc[2][4];
#pragma unroll
    for (int a = 0; a < 2; ++a)
#pragma unroll
        for (int b = 0; b < 4; ++b) acc[a][b] = (f32x4v){0.f, 0.f, 0.f, 0.f};

    const _Float16* XA = Xh + (size_t)(row0 + r16) * 256 + kseg * 4;
    const _Float16* WB = Wt + (size_t)(w * 64 + r16) * 256 + kseg * 4;

    f16x4 a0[2], a1[2], b0[2], b1[2], b2[2], b3[2];
#define LOADF(st, koff)                                   \
    a0[st] = *(const f16x4*)(XA + (koff));                \
    a1[st] = *(const f16x4*)(XA + 16 * 256 + (koff));     \
    b0[st] = *(const f16x4*)(WB + (koff));                \
    b1[st] = *(const f16x4*)(WB + 16 * 256 + (koff));     \
    b2[st] = *(const f16x4*)(WB + 32 * 256 + (koff));     \
    b3[st] = *(const f16x4*)(WB + 48 * 256 + (koff));

    LOADF(0, 0)
#pragma unroll
    for (int s = 0; s < 16; ++s) {
        const int cur = s & 1, nxt = cur ^ 1;
        if (s < 15) { LOADF(nxt, (s + 1) * 16) }
        acc[0][0] = __builtin_amdgcn_mfma_f32_16x16x16f16(a0[cur], b0[cur], acc[0][0], 0, 0, 0);
        acc[0][1] = __builtin_amdgcn_mfma_f32_16x16x16f16(a0[cur], b1[cur], acc[0][1], 0, 0, 0);
        acc[0][2] = __builtin_amdgcn_mfma_f32_16x16x16f16(a0[cur], b2[cur], acc[0][2], 0, 0, 0);
        acc[0][3] = __builtin_amdgcn_mfma_f32_16x16x16f16(a0[cur], b3[cur], acc[0][3], 0, 0, 0);
        acc[1][0] = __builtin_amdgcn_mfma_f32_16x16x16f16(a1[cur], b0[cur], acc[1][0], 0, 0, 0);
        acc[1][1] = __builtin_amdgcn_mfma_f32_16x16x16f16(a1[cur], b1[cur], acc[1][1], 0, 0, 0);
        acc[1][2] = __builtin_amdgcn_mfma_f32_16x16x16f16(a1[cur], b2[cur], acc[1][2], 0, 0, 0);
        acc[1][3] = __builtin_amdgcn_mfma_f32_16x16x16f16(a1[cur], b3[cur], acc[1][3], 0, 0, 0);
    }
#undef LOADF

    // fused attention-score dots: wave w's 64 cols = heads 2w, 2w+1 complete
    float as0 = a_src[w * 64 + r16],      as1 = a_src[w * 64 + 16 + r16];
    float as2 = a_src[w * 64 + 32 + r16], as3 = a_src[w * 64 + 48 + r16];
    float ad0 = a_dst[w * 64 + r16],      ad1 = a_dst[w * 64 + 16 + r16];
    float ad2 = a_dst[w * 64 + 32 + r16], ad3 = a_dst[w * 64 + 48 + r16];
#pragma unroll
    for (int tm = 0; tm < 2; ++tm) {
#pragma unroll
        for (int r = 0; r < 4; ++r) {
            float p0 = acc[tm][0][r] * as0 + acc[tm][1][r] * as1;
            float p1 = acc[tm][2][r] * as2 + acc[tm][3][r] * as3;
            float q0 = acc[tm][0][r] * ad0 + acc[tm][1][r] * ad1;
            float q1 = acc[tm][2][r] * ad2 + acc[tm][3][r] * ad3;
#pragma unroll
            for (int m = 1; m < 16; m <<= 1) {
                p0 += __shfl_xor(p0, m); p1 += __shfl_xor(p1, m);
                q0 += __shfl_xor(q0, m); q1 += __shfl_xor(q1, m);
            }
            if (r16 == 0) {
                int row = row0 + tm * 16 + kseg * 4 + r;
                ssrc[row * NH + w * 2]     = p0;
                ssrc[row * NH + w * 2 + 1] = p1;
                sdst[row * NH + w * 2]     = q0;
                sdst[row * NH + w * 2 + 1] = q1;
            }
        }
    }

    // H (fp16) via LDS transpose for coalesced 16B stores
#pragma unroll
    for (int tm = 0; tm < 2; ++tm)
#pragma unroll
        for (int tn = 0; tn < 4; ++tn)
#pragma unroll
            for (int r = 0; r < 4; ++r)
                hs[(tm * 16 + kseg * 4 + r) * 264 + w * 64 + tn * 16 + r16] = (_Float16)acc[tm][tn][r];
    __syncthreads();
#pragma unroll
    for (int i = 0; i < 4; ++i) {
        int idx = i * 256 + tid;
        int rr = idx >> 5;
        int cc = idx & 31;
        f16x8 v = *(const f16x8*)&hs[rr * 264 + cc * 8];
        *(f16x8*)(Hh + (size_t)(row0 + rr) * 256 + cc * 8) = v;
    }
}

// ---------------- GEMM K=41 (fp32 VALU) + fused score dots, fp16 H out ----------------

__global__ __launch_bounds__(256) void gemm41(const float* __restrict__ X,
                                              const float* __restrict__ W,
                                              const float* __restrict__ a_src,
                                              const float* __restrict__ a_dst,
                                              _Float16* __restrict__ Hh,
                                              float* __restrict__ ssrc,
                                              float* __restrict__ sdst) {
    __shared__ float xs[32][44];
    int row0 = blockIdx.x * 32;
    int tid = threadIdx.x;
    int lane = tid & 63;
    int wave = tid >> 6;
    int c4 = lane * 4;
    int wrow = wave * 8;

    for (int idx = tid; idx < 32 * FIN; idx += 256) {
        int r = idx / FIN, k = idx - r * FIN;
        xs[r][k] = X[(size_t)(row0 + r) * FIN + k];
    }
    __syncthreads();

    float4 acc[8];
#pragma unroll
    for (int r = 0; r < 8; ++r) acc[r] = make_float4(0.f, 0.f, 0.f, 0.f);

    for (int k = 0; k < FIN; ++k) {
        float4 w0 = *reinterpret_cast<const float4*>(W + (size_t)k * HC + c4);
#pragma unroll
        for (int r = 0; r < 8; ++r) {
            float xv = xs[wrow + r][k];
            acc[r].x += xv * w0.x; acc[r].y += xv * w0.y; acc[r].z += xv * w0.z; acc[r].w += xv * w0.w;
        }
    }
    const float4 asv = *reinterpret_cast<const float4*>(a_src + c4);
    const float4 adv = *reinterpret_cast<const float4*>(a_dst + c4);
#pragma unroll
    for (int r = 0; r < 8; ++r) {
        int gr = row0 + wrow + r;
        f16x4 hv;
        hv[0] = (_Float16)acc[r].x; hv[1] = (_Float16)acc[r].y;
        hv[2] = (_Float16)acc[r].z; hv[3] = (_Float16)acc[r].w;
        *(f16x4*)(Hh + (size_t)gr * HC + c4) = hv;
        float ps = acc[r].x * asv.x + acc[r].y * asv.y + acc[r].z * asv.z + acc[r].w * asv.w;
        float pd = acc[r].x * adv.x + acc[r].y * adv.y + acc[r].z * adv.z + acc[r].w * adv.w;
        ps += __shfl_xor(ps, 1); pd += __shfl_xor(pd, 1);
        ps += __shfl_xor(ps, 2); pd += __shfl_xor(pd, 2);
        ps += __shfl_xor(ps, 4); pd += __shfl_xor(pd, 4);
        if ((lane & 7) == 0) {
            ssrc[gr * NH + (lane >> 3)] = ps;
            sdst[gr * NH + (lane >> 3)] = pd;
        }
    }
}

// ---------------- fused GAT aggregation + bias + BN(eval) + ELU ----------------

template <int OUTH>
__global__ __launch_bounds__(256) void gat_agg(const int* __restrict__ row_ptr,
                                               const int* __restrict__ colidx,
                                               const float* __restrict__ ssrc,
                                               const float* __restrict__ sdst,
                                               const _Float16* __restrict__ h,
                                               const float* __restrict__ bias,
                                               const float* __restrict__ gamma,
                                               const float* __restrict__ beta,
                                               float* __restrict__ out,
                                               _Float16* __restrict__ outh) {
    int wave = (blockIdx.x * blockDim.x + threadIdx.x) >> 6;
    int lane = threadIdx.x & 63;
    if (wave >= N_NODES) return;
    int n = wave;
    int beg = row_ptr[n], end = row_ptr[n + 1];
    int deg = end - beg;

    int hd1 = lane & 7;
    float sd1 = sdst[n * NH + hd1];
    float mx = -3.0e38f;
    for (int i = (lane >> 3); i < deg; i += 8) {
        int s = colidx[beg + i];
        float v = ssrc[s * NH + hd1] + sd1;
        v = (v >= 0.f) ? v : 0.2f * v;
        mx = fmaxf(mx, v);
    }
    mx = fmaxf(mx, __shfl_xor(mx, 8));
    mx = fmaxf(mx, __shfl_xor(mx, 16));
    mx = fmaxf(mx, __shfl_xor(mx, 32));

    int hd2 = lane >> 3;
    float m2 = __shfl(mx, hd2);
    float sd2 = sdst[n * NH + hd2];
    int c = lane * 4;
    float acc0 = 0.f, acc1 = 0.f, acc2 = 0.f, acc3 = 0.f, denom = 0.f;

    int i = 0;
    for (; i + 4 <= deg; i += 4) {
        int s0 = colidx[beg + i];
        int s1 = colidx[beg + i + 1];
        int s2 = colidx[beg + i + 2];
        int s3 = colidx[beg + i + 3];
        float v0 = ssrc[s0 * NH + hd2] + sd2; v0 = (v0 >= 0.f) ? v0 : 0.2f * v0;
        float v1 = ssrc[s1 * NH + hd2] + sd2; v1 = (v1 >= 0.f) ? v1 : 0.2f * v1;
        float v2 = ssrc[s2 * NH + hd2] + sd2; v2 = (v2 >= 0.f) ? v2 : 0.2f * v2;
        float v3 = ssrc[s3 * NH + hd2] + sd2; v3 = (v3 >= 0.f) ? v3 : 0.2f * v3;
        float w0 = __expf(v0 - m2);
        float w1 = __expf(v1 - m2);
        float w2 = __expf(v2 - m2);
        float w3 = __expf(v3 - m2);
        const f16x4 h0 = *reinterpret_cast<const f16x4*>(h + (size_t)s0 * HC + c);
        const f16x4 h1 = *reinterpret_cast<const f16x4*>(h + (size_t)s1 * HC + c);
        const f16x4 h2 = *reinterpret_cast<const f16x4*>(h + (size_t)s2 * HC + c);
        const f16x4 h3 = *reinterpret_cast<const f16x4*>(h + (size_t)s3 * HC + c);
        denom += (w0 + w1) + (w2 + w3);
        acc0 += w0 * (float)h0[0] + w1 * (float)h1[0] + w2 * (float)h2[0] + w3 * (float)h3[0];
        acc1 += w0 * (float)h0[1] + w1 * (float)h1[1] + w2 * (float)h2[1] + w3 * (float)h3[1];
        acc2 += w0 * (float)h0[2] + w1 * (float)h1[2] + w2 * (float)h2[2] + w3 * (float)h3[2];
        acc3 += w0 * (float)h0[3] + w1 * (float)h1[3] + w2 * (float)h2[3] + w3 * (float)h3[3];
    }
    for (; i < deg; ++i) {
        int s = colidx[beg + i];
        float v = ssrc[s * NH + hd2] + sd2;
        v = (v >= 0.f) ? v : 0.2f * v;
        float wgt = __expf(v - m2);
        denom += wgt;
        const f16x4 hv = *reinterpret_cast<const f16x4*>(h + (size_t)s * HC + c);
        acc0 += wgt * (float)hv[0]; acc1 += wgt * (float)hv[1];
        acc2 += wgt * (float)hv[2]; acc3 += wgt * (float)hv[3];
    }
    float inv = 1.0f / denom;
    const float bninv = 0.99999500003749981f;  // 1/sqrt(1+1e-5)
    float vals[4] = {acc0, acc1, acc2, acc3};
    float res[4];
#pragma unroll
    for (int j = 0; j < 4; ++j) {
        float v = vals[j] * inv + bias[c + j];
        v = v * (gamma[c + j] * bninv) + beta[c + j];
        v = (v > 0.f) ? v : (__expf(v) - 1.0f);
        res[j] = v;
    }
    if (OUTH) {
        f16x4 o;
        o[0] = (_Float16)res[0]; o[1] = (_Float16)res[1];
        o[2] = (_Float16)res[2]; o[3] = (_Float16)res[3];
        *(f16x4*)(outh + (size_t)n * HC + c) = o;
    } else {
        float4 o = make_float4(res[0], res[1], res[2], res[3]);
        *reinterpret_cast<float4*>(out + (size_t)n * HC + c) = o;
    }
}

// ---------------- pooling ----------------

__global__ __launch_bounds__(256) void graph_ranges(const int* __restrict__ batch, int* gstart, int* gend) {
    int n = blockIdx.x * 256 + threadIdx.x;
    if (n >= N_NODES) return;
    int b = batch[n];
    if (n == 0) gstart[b] = 0;
    else {
        int pb = batch[n - 1];
        if (pb != b) { gstart[b] = n; gend[pb] = n; }
    }
    if (n == N_NODES - 1) gend[b] = N_NODES;
}

__global__ __launch_bounds__(256) void pool_partial(const float* __restrict__ h,
                                                    const int* __restrict__ gstart,
                                                    const int* __restrict__ gend,
                                                    float* __restrict__ psum,
                                                    float* __restrict__ pmax) {
    int g = blockIdx.x >> 4;
    int c = blockIdx.x & (PCHUNK - 1);
    int t = threadIdx.x;
    int s = gstart[g], e = gend[g];
    int len = e - s;
    int n0 = s + (int)(((long long)len * c) / PCHUNK);
    int n1 = s + (int)(((long long)len * (c + 1)) / PCHUNK);
    float sum = 0.f, mx = -3.0e38f;
    for (int n = n0; n < n1; ++n) {
        float v = h[(size_t)n * HC + t];
        sum += v;
        mx = fmaxf(mx, v);
    }
    psum[(size_t)(g * PCHUNK + c) * HC + t] = sum;
    pmax[(size_t)(g * PCHUNK + c) * HC + t] = mx;
}

// ---------------- MLP head (fused pool-finalize + 3 FC layers) ----------------
// fc1 computed output-per-wave with transposed weights (coalesced float4 loads).

__global__ __launch_bounds__(256) void mlp(const float* __restrict__ psum,
                                           const float* __restrict__ pmax,
                                           const int* __restrict__ gstart,
                                           const int* __restrict__ gend,
                                           const float* __restrict__ gsz,
                                           const float* __restrict__ fc1wT, const float* __restrict__ fc1b,
                                           const float* __restrict__ gf1, const float* __restrict__ bf1,
                                           const float* __restrict__ fc2w, const float* __restrict__ fc2b,
                                           const float* __restrict__ gf2, const float* __restrict__ bf2,
                                           const float* __restrict__ fc3w, const float* __restrict__ fc3b,
                                           float* __restrict__ out) {
    __shared__ __align__(16) float pr[514];
    __shared__ float z1[64];
    __shared__ float zz2[8][32];
    __shared__ float z2[32];
    int g = blockIdx.x;
    int t = threadIdx.x;
    const float bninv = 0.99999500003749981f;

    // phase 0: reduce pool partials
    {
        float s = 0.f, m = -3.0e38f;
#pragma unroll
        for (int c = 0; c < PCHUNK; ++c) {
            s += psum[(size_t)(g * PCHUNK + c) * HC + t];
            m = fmaxf(m, pmax[(size_t)(g * PCHUNK + c) * HC + t]);
        }
        float cnt = (float)(gend[g] - gstart[g]);
        pr[t] = s / fmaxf(cnt, 1.f);
        pr[256 + t] = m;
        if (t < 2) pr[512 + t] = gsz[g * 2 + t];
    }
    __syncthreads();

    // phase 1: fc1 (514 x 64): wave wv computes outputs wv*16..wv*16+15.
    // lane reads 32B contiguous of fc1wT row (coalesced), shfl-reduce.
    {
        int wv = t >> 6, lane = t & 63;
        float4 pa = *reinterpret_cast<const float4*>(&pr[lane * 8]);
        float4 pb = *reinterpret_cast<const float4*>(&pr[lane * 8 + 4]);
#pragma unroll 4
        for (int i = 0; i < 16; ++i) {
            int u = wv * 16 + i;
            const float* wrow = fc1wT + u * 520;
            float4 wa = *reinterpret_cast<const float4*>(wrow + lane * 8);
            float4 wb = *reinterpret_cast<const float4*>(wrow + lane * 8 + 4);
            float a = pa.x * wa.x + pa.y * wa.y + pa.z * wa.z + pa.w * wa.w
                    + pb.x * wb.x + pb.y * wb.y + pb.z * wb.z + pb.w * wb.w;
            if (lane == 0) a += pr[512] * wrow[512] + pr[513] * wrow[513];
            a += __shfl_xor(a, 1); a += __shfl_xor(a, 2); a += __shfl_xor(a, 4);
            a += __shfl_xor(a, 8); a += __shfl_xor(a, 16); a += __shfl_xor(a, 32);
            if (lane == 0) {
                a += fc1b[u];
                a = a * (gf1[u] * bninv) + bf1[u];
                z1[u] = fmaxf(a, 0.f);
            }
        }
    }
    __syncthreads();

    // phase 2: fc2 (64 x 32), 8-way k-split
    {
        int u = t & 31, sp = t >> 5;
        float b = 0.f;
#pragma unroll
        for (int k = sp * 8; k < sp * 8 + 8; ++k) b += z1[k] * fc2w[k * 32 + u];
        zz2[sp][u] = b;
    }
    __syncthreads();
    if (t < 32) {
        float b = 0.f;
#pragma unroll
        for (int sp = 0; sp < 8; ++sp) b += zz2[sp][t];
        b += fc2b[t];
        b = b * (gf2[t] * bninv) + bf2[t];
        z2[t] = fmaxf(b, 0.f);
    }
    __syncthreads();

    // phase 3: fc3 (32 x 2)
    if (t < 2) {
        float c = 0.f;
#pragma unroll
        for (int k = 0; k < 32; ++k) c += z2[k] * fc3w[k * 2 + t];
        out[g * 2 + t] = c + fc3b[t];
    }
}

// ---------------- launch ----------------

extern "C" void kernel_launch(void* const* d_in, const int* in_sizes, int n_in,
                              void* d_out, int out_size, void* d_ws, size_t ws_size,
                              hipStream_t stream) {
    const float* x    = (const float*)d_in[0];
    const int*   ei   = (const int*)d_in[1];
    const int*   batch= (const int*)d_in[2];
    const float* gsz  = (const float*)d_in[3];
    const float* W1   = (const float*)d_in[4];
    const float* as1  = (const float*)d_in[5];
    const float* ad1  = (const float*)d_in[6];
    const float* b1   = (const float*)d_in[7];
    const float* g1   = (const float*)d_in[8];
    const float* be1  = (const float*)d_in[9];
    const float* W2   = (const float*)d_in[10];
    const float* as2  = (const float*)d_in[11];
    const float* ad2  = (const float*)d_in[12];
    const float* b2   = (const float*)d_in[13];
    const float* g2   = (const float*)d_in[14];
    const float* be2  = (const float*)d_in[15];
    const float* fc1w = (const float*)d_in[16];
    const float* fc1b = (const float*)d_in[17];
    const float* gf1  = (const float*)d_in[18];
    const float* bf1  = (const float*)d_in[19];
    const float* fc2w = (const float*)d_in[20];
    const float* fc2b = (const float*)d_in[21];
    const float* gf2  = (const float*)d_in[22];
    const float* bf2  = (const float*)d_in[23];
    const float* fc3w = (const float*)d_in[24];
    const float* fc3b = (const float*)d_in[25];
    float* out = (float*)d_out;

    char* w = (char*)d_ws;
    _Float16* h_half   = (_Float16*)w; w += (size_t)N_NODES * HC * 2;   // 10.24 MB
    _Float16* act_half = (_Float16*)w; w += (size_t)N_NODES * HC * 2;   // 10.24 MB
    float* actbuf      = (float*)w;    w += (size_t)N_NODES * HC * 4;   // 20.48 MB (pool in)
    _Float16* Wt       = (_Float16*)w; w += (size_t)HC * HC * 2;        // 128 KB
    float* fc1wT       = (float*)w;    w += (size_t)64 * 520 * 4;       // 133 KB
    float* ssrc        = (float*)w;    w += (size_t)N_NODES * NH * 4;
    float* sdst        = (float*)w;    w += (size_t)N_NODES * NH * 4;
    int* row_ptr  = (int*)w;   w += (size_t)(N_NODES + 1) * 4;
    int* cursor   = (int*)w;   w += (size_t)N_NODES * 4;
    int* cnt      = (int*)w;   w += (size_t)N_NODES * 4;
    int* colidx   = (int*)w;   w += (size_t)(E_EDGES + N_NODES) * 4;
    int* partial  = (int*)w;   w += 64 * 4;
    int* gstart   = (int*)w;   w += 64 * 4;
    int* gend     = (int*)w;   w += 64 * 4;

    // pool partials alias h_half (dead after gat_agg#2)
    float* psum = (float*)h_half;
    float* pmax = psum + (size_t)NG * PCHUNK * HC;

    hipMemsetAsync(gstart, 0, 2 * 64 * 4, stream);

    init_counts<<<79, 256, 0, stream>>>(cnt);
    hist<<<1250, 256, 0, stream>>>(ei, cnt);
    scanA<<<40, 512, 0, stream>>>(cnt, partial);
    scanB<<<1, 64, 0, stream>>>(partial);
    scanC<<<40, 512, 0, stream>>>(cnt, partial, row_ptr, cursor, colidx);
    fill_csr<<<1250, 256, 0, stream>>>(ei, cursor, colidx);
    wconv<<<16, 256, 0, stream>>>(W2, Wt);
    fc1conv<<<129, 256, 0, stream>>>(fc1w, fc1wT);

    gemm41<<<625, 256, 0, stream>>>(x, W1, as1, ad1, h_half, ssrc, sdst);
    gat_agg<1><<<5000, 256, 0, stream>>>(row_ptr, colidx, ssrc, sdst, h_half, b1, g1, be1,
                                         (float*)nullptr, act_half);

    gemm256h<<<625, 256, 0, stream>>>(act_half, Wt, as2, ad2, h_half, ssrc, sdst);
    gat_agg<0><<<5000, 256, 0, stream>>>(row_ptr, colidx, ssrc, sdst, h_half, b2, g2, be2,
                                         actbuf, (_Float16*)nullptr);

    graph_ranges<<<79, 256, 0, stream>>>(batch, gstart, gend);
    pool_partial<<<NG * PCHUNK, 256, 0, stream>>>(actbuf, gstart, gend, psum, pmax);
    mlp<<<NG, 256, 0, stream>>>(psum, pmax, gstart, gend, gsz,
                                fc1wT, fc1b, gf1, bf1, fc2w, fc2b, gf2, bf2, fc3w, fc3b, out);
}